// Round 4
// baseline (4746.276 us; speedup 1.0000x reference)
//
#include <hip/hip_runtime.h>
#include <stdint.h>

typedef short bf16x8 __attribute__((ext_vector_type(8)));
typedef float f32x4 __attribute__((ext_vector_type(4)));

__device__ __forceinline__ unsigned short f2bf(float f) {
  union { float f; unsigned int i; } v; v.f = f;
  unsigned int r = v.i + 0x7FFF + ((v.i >> 16) & 1);
  return (unsigned short)(r >> 16);
}
__device__ __forceinline__ float bfu2f(unsigned short u) {
  union { unsigned int i; float f; } v; v.i = ((unsigned int)u) << 16; return v.f;
}
__device__ __forceinline__ void gload_lds16(const void* g, void* l) {
  __builtin_amdgcn_global_load_lds(
      (const __attribute__((address_space(1))) unsigned int*)g,
      (__attribute__((address_space(3))) unsigned int*)l,
      16, 0, 0);
}

// ---------------- convert f32 weights -> bf16 (Whh0, Wih1, Whh1, Wout) ----------------
__global__ __launch_bounds__(256) void k_cvt(const float* __restrict__ s0, const float* __restrict__ s1,
                                             const float* __restrict__ s2, const float* __restrict__ s3,
                                             unsigned short* __restrict__ d0, unsigned short* __restrict__ d1,
                                             unsigned short* __restrict__ d2, unsigned short* __restrict__ d3) {
  int j = blockIdx.x * 256 + threadIdx.x;   // 6656*256 = 1,703,936 vec8 jobs exactly
  const float* s; unsigned short* d; int o;
  if (j < 524288)       { s = s0; d = d0; o = j; }
  else if (j < 1048576) { s = s1; d = d1; o = j - 524288; }
  else if (j < 1572864) { s = s2; d = d2; o = j - 1048576; }
  else                  { s = s3; d = d3; o = j - 1572864; }
  size_t off = (size_t)o * 8;
  f32x4 v0 = *(const f32x4*)(s + off);
  f32x4 v1 = *(const f32x4*)(s + off + 4);
  bf16x8 r;
#pragma unroll
  for (int k = 0; k < 4; k++) { r[k] = (short)f2bf(v0[k]); r[4 + k] = (short)f2bf(v1[k]); }
  *(bf16x8*)(d + off) = r;
}

// ---------------- prep: embedding gather (f32) + zero state + zero barrier ----------------
__global__ __launch_bounds__(256) void k_prep(const int* __restrict__ ys,
                                              const float* __restrict__ embed,
                                              float* __restrict__ eys,
                                              float* __restrict__ h0h, float* __restrict__ h1h,
                                              int* __restrict__ bar) {
  int idx = blockIdx.x * 256 + threadIdx.x;   // 16384 threads
  int row = idx >> 6;
  int e = (idx & 63) * 8;
  int y = ys[row];
  f32x4 v0 = {0.f, 0.f, 0.f, 0.f}, v1 = {0.f, 0.f, 0.f, 0.f};
  if (y != 0) {
    v0 = *(const f32x4*)(embed + (size_t)y * 512 + e);
    v1 = *(const f32x4*)(embed + (size_t)y * 512 + e + 4);
  }
  *(f32x4*)(eys + (size_t)row * 512 + e) = v0;
  *(f32x4*)(eys + (size_t)row * 512 + e + 4) = v1;
  if (idx < 4096) { h0h[idx] = 0.f; h1h[idx] = 0.f; }
  if (idx == 8192) bar[0] = 0;
}

// -------- generic small GEMM: C(f32 MxN) = A(f32 MxK) @ W(f32 NxK)^T + b1 + b2 --------
__global__ __launch_bounds__(256) void k_gemm_bias(const float* __restrict__ A,
                                                   const float* __restrict__ W,
                                                   const float* __restrict__ b1,
                                                   const float* __restrict__ b2,
                                                   float* __restrict__ C,
                                                   int M, int N, int K) {
  __shared__ unsigned short Als[64][40];
  __shared__ unsigned short Wls[64][40];
  int tid = threadIdx.x;
  int lane = tid & 63, wid = tid >> 6;
  int mtiles = M >> 6;
  int mt = blockIdx.x % mtiles, nt = blockIdx.x / mtiles;
  int srow = tid >> 2, sseg = tid & 3;
  f32x4 acc[4];
#pragma unroll
  for (int nf = 0; nf < 4; nf++) acc[nf] = (f32x4){0.f, 0.f, 0.f, 0.f};

  for (int kc = 0; kc < K; kc += 32) {
    const float* ap = A + (size_t)(mt * 64 + srow) * K + kc + sseg * 8;
    const float* wp = W + (size_t)(nt * 64 + srow) * K + kc + sseg * 8;
    f32x4 a0 = *(const f32x4*)ap, a1 = *(const f32x4*)(ap + 4);
    f32x4 w0 = *(const f32x4*)wp, w1 = *(const f32x4*)(wp + 4);
    bf16x8 av, wv;
#pragma unroll
    for (int k = 0; k < 4; k++) {
      av[k] = (short)f2bf(a0[k]); av[4 + k] = (short)f2bf(a1[k]);
      wv[k] = (short)f2bf(w0[k]); wv[4 + k] = (short)f2bf(w1[k]);
    }
    __syncthreads();
    *(bf16x8*)(&Als[srow][sseg * 8]) = av;
    *(bf16x8*)(&Wls[srow][sseg * 8]) = wv;
    __syncthreads();
    bf16x8 af = *(const bf16x8*)(&Als[wid * 16 + (lane & 15)][(lane >> 4) * 8]);
#pragma unroll
    for (int nf = 0; nf < 4; nf++) {
      bf16x8 bf = *(const bf16x8*)(&Wls[nf * 16 + (lane & 15)][(lane >> 4) * 8]);
      acc[nf] = __builtin_amdgcn_mfma_f32_16x16x32_bf16(af, bf, acc[nf], 0, 0, 0);
    }
  }
  int rloc = (lane >> 4) * 4;
  int col0 = lane & 15;
#pragma unroll
  for (int nf = 0; nf < 4; nf++) {
    int n = nt * 64 + nf * 16 + col0;
    float bias = 0.f;
    if (b1) bias += b1[n];
    if (b2) bias += b2[n];
#pragma unroll
    for (int r = 0; r < 4; r++) {
      int m = mt * 64 + wid * 16 + rloc + r;
      C[(size_t)m * N + n] = acc[nf][r] + bias;
    }
  }
}

// ---------------- fused LSTM: 65 pipelined phases in one persistent kernel ----------------
// grid 256 x 512 threads. Blocks 0..127: layer0 (8 ch each). 128..255: layer1 (8 ch each).
// Weights preconverted to f32 and held in registers across all phases.
__device__ __forceinline__ void gridbar(int* bar, int target, int tid) {
  __threadfence();                 // agent-scope release: push h writes to coherence point
  __syncthreads();
  if (tid == 0) {
    __hip_atomic_fetch_add(bar, 1, __ATOMIC_ACQ_REL, __HIP_MEMORY_SCOPE_AGENT);
    while (__hip_atomic_load(bar, __ATOMIC_ACQUIRE, __HIP_MEMORY_SCOPE_AGENT) < target)
      __builtin_amdgcn_s_sleep(2);
  }
  __syncthreads();
}

__global__ __launch_bounds__(512, 2) void k_lstm_fused(
    const float* __restrict__ X0,            // (B,U,4096)  eys@Wih0^T + bih0 + bhh0
    float* __restrict__ h0h,                 // (65,B,1024)
    float* __restrict__ h1h,                 // (65,B,1024)
    float* __restrict__ hdec,                // (B,U,1024) f32
    const unsigned short* __restrict__ W_hh0,
    const unsigned short* __restrict__ W_ih1,
    const unsigned short* __restrict__ W_hh1,
    const float* __restrict__ b_ih1,
    const float* __restrict__ b_hh1,
    int* __restrict__ bar) {
  __shared__ float xs[2 * 4096];       // 32 KB
  __shared__ float red[16][32][4];     // 8 KB
  __shared__ float gsum[32][4];
  int tid = threadIdx.x;
  bool is1 = blockIdx.x >= 128;
  int base = (blockIdx.x & 127) * 8;
  int s = tid >> 5;          // 0..15  K-segment
  int r = tid & 31;          // 0..31  row = gate*8 + ch
  int g = r >> 3, cl = r & 7;
  int wrow = g * 1024 + base + cl;

  // ---- preload + convert weights to f32 registers (held across all phases) ----
  float wf[16][8];
  const float* xb;
  if (!is1) {
    const unsigned short* wptr = W_hh0 + (size_t)wrow * 1024 + s * 64;
#pragma unroll
    for (int i = 0; i < 8; i++) {
      bf16x8 wv = *(const bf16x8*)(wptr + i * 8);
#pragma unroll
      for (int j = 0; j < 8; j++) wf[i][j] = bfu2f((unsigned short)wv[j]);
    }
    xb = xs + s * 64;
  } else {
    const unsigned short* wptr = (s < 8) ? (W_ih1 + (size_t)wrow * 1024 + s * 128)
                                         : (W_hh1 + (size_t)wrow * 1024 + (s - 8) * 128);
#pragma unroll
    for (int i = 0; i < 16; i++) {
      bf16x8 wv = *(const bf16x8*)(wptr + i * 8);
#pragma unroll
      for (int j = 0; j < 8; j++) wf[i][j] = bfu2f((unsigned short)wv[j]);
    }
    xb = (s < 8) ? (xs + s * 128) : (xs + 4096 + (s - 8) * 128);
  }

  // per-thread persistent cell state (tid<32: ch = base + (tid>>2), b = tid&3)
  float creg = 0.f;
  float bsum0 = 0.f, bsum1 = 0.f, bsum2 = 0.f, bsum3 = 0.f;
  if (is1 && tid < 32) {
    int ch = base + (tid >> 2);
    bsum0 = b_ih1[ch] + b_hh1[ch];
    bsum1 = b_ih1[1024 + ch] + b_hh1[1024 + ch];
    bsum2 = b_ih1[2048 + ch] + b_hh1[2048 + ch];
    bsum3 = b_ih1[3072 + ch] + b_hh1[3072 + ch];
  }

  for (int p = 0; p < 65; p++) {
    bool active = is1 ? (p >= 1) : (p < 64);
    if (active) {
      // ---- stage x vectors into LDS ----
      for (int i = tid; i < 1024; i += 512)
        ((f32x4*)xs)[i] = ((const f32x4*)(h0h + (size_t)p * 4096))[i];
      if (is1)
        for (int i = tid; i < 1024; i += 512)
          ((f32x4*)(xs + 4096))[i] = ((const f32x4*)(h1h + (size_t)(p - 1) * 4096))[i];
      __syncthreads();

      // ---- GEMV partials ----
      float a0 = 0.f, a1 = 0.f, a2 = 0.f, a3 = 0.f;
      if (!is1) {
#pragma unroll
        for (int i = 0; i < 8; i++) {
          f32x4 x00 = *(const f32x4*)(xb + i * 8);
          f32x4 x01 = *(const f32x4*)(xb + i * 8 + 4);
          f32x4 x10 = *(const f32x4*)(xb + 1024 + i * 8);
          f32x4 x11 = *(const f32x4*)(xb + 1024 + i * 8 + 4);
          f32x4 x20 = *(const f32x4*)(xb + 2048 + i * 8);
          f32x4 x21 = *(const f32x4*)(xb + 2048 + i * 8 + 4);
          f32x4 x30 = *(const f32x4*)(xb + 3072 + i * 8);
          f32x4 x31 = *(const f32x4*)(xb + 3072 + i * 8 + 4);
#pragma unroll
          for (int j = 0; j < 4; j++) {
            a0 += wf[i][j] * x00[j]; a1 += wf[i][j] * x10[j];
            a2 += wf[i][j] * x20[j]; a3 += wf[i][j] * x30[j];
          }
#pragma unroll
          for (int j = 0; j < 4; j++) {
            a0 += wf[i][4 + j] * x01[j]; a1 += wf[i][4 + j] * x11[j];
            a2 += wf[i][4 + j] * x21[j]; a3 += wf[i][4 + j] * x31[j];
          }
        }
      } else {
#pragma unroll
        for (int i = 0; i < 16; i++) {
          f32x4 x00 = *(const f32x4*)(xb + i * 8);
          f32x4 x01 = *(const f32x4*)(xb + i * 8 + 4);
          f32x4 x10 = *(const f32x4*)(xb + 1024 + i * 8);
          f32x4 x11 = *(const f32x4*)(xb + 1024 + i * 8 + 4);
          f32x4 x20 = *(const f32x4*)(xb + 2048 + i * 8);
          f32x4 x21 = *(const f32x4*)(xb + 2048 + i * 8 + 4);
          f32x4 x30 = *(const f32x4*)(xb + 3072 + i * 8);
          f32x4 x31 = *(const f32x4*)(xb + 3072 + i * 8 + 4);
#pragma unroll
          for (int j = 0; j < 4; j++) {
            a0 += wf[i][j] * x00[j]; a1 += wf[i][j] * x10[j];
            a2 += wf[i][j] * x20[j]; a3 += wf[i][j] * x30[j];
          }
#pragma unroll
          for (int j = 0; j < 4; j++) {
            a0 += wf[i][4 + j] * x01[j]; a1 += wf[i][4 + j] * x11[j];
            a2 += wf[i][4 + j] * x21[j]; a3 += wf[i][4 + j] * x31[j];
          }
        }
      }
      *(f32x4*)&red[s][r][0] = (f32x4){a0, a1, a2, a3};
      __syncthreads();
      if (tid < 128) {
        int rr = tid >> 2, b = tid & 3;
        float sum = 0.f;
#pragma unroll
        for (int ss = 0; ss < 16; ss++) sum += red[ss][rr][b];
        gsum[rr][b] = sum;
      }
      __syncthreads();
      if (tid < 32) {
        int cl2 = tid >> 2, b = tid & 3;
        int ch = base + cl2;
        float gi = gsum[cl2][b], gf = gsum[8 + cl2][b];
        float gg = gsum[16 + cl2][b], go = gsum[24 + cl2][b];
        if (!is1) {
          const float* x0p = X0 + ((size_t)(b * 64 + p)) * 4096;
          gi += x0p[ch]; gf += x0p[1024 + ch]; gg += x0p[2048 + ch]; go += x0p[3072 + ch];
        } else {
          gi += bsum0; gf += bsum1; gg += bsum2; go += bsum3;
        }
        float ii = 1.f / (1.f + __expf(-gi));
        float ff = 1.f / (1.f + __expf(-gf));
        float oo = 1.f / (1.f + __expf(-go));
        float cn = ff * creg + ii * tanhf(gg);
        creg = cn;
        float hn = oo * tanhf(cn);
        if (!is1) {
          h0h[(size_t)(p + 1) * 4096 + b * 1024 + ch] = hn;
        } else {
          h1h[(size_t)p * 4096 + b * 1024 + ch] = hn;
          hdec[((size_t)(b * 64 + (p - 1))) * 1024 + ch] = hn;
        }
      }
    }
    if (p < 64) gridbar(bar, (p + 1) * 256, tid);
  }
}

// ---------------- joint: out[b,t,u,:] = tanh(encp[b,t,:]+decp[b,u,:]) @ Wout^T + bout ----
// 256 blocks x 512 threads; z-panel in regs; NONTEMPORAL f32 output stores.
__global__ __launch_bounds__(512) void k_joint(const float* __restrict__ encp,   // (B,T,512)
                                               const float* __restrict__ decp,   // (B,U,512)
                                               const unsigned short* __restrict__ Wout, // (2048,512) bf16
                                               const float* __restrict__ bout,   // (2048) f32
                                               float* __restrict__ out) {        // (B,T,U,2048) f32
  __shared__ unsigned short Wls[2][8192];   // 2 x 16KB: 128 n-rows x 64 k (swizzled)
  int tid = threadIdx.x;
  int lane = tid & 63, wid = tid >> 6;      // 8 waves
  int bidx = blockIdx.x;
  int b = bidx >> 6, tloc = bidx & 63;
  int t0 = tloc * 2;
  int wm = (wid >> 1) * 32;                 // 4 m-waves x 32 rows
  int wn = (wid & 1) * 64;                  // 2 n-waves x 64 cols

  // ---- prologue: issue stage of chunk 0 (overlaps with A-build) ----
  {
#pragma unroll
    for (int q = 0; q < 2; q++) {
      int idx = tid + q * 512;
      int n = idx >> 3, sl = idx & 7;
      int ss = sl ^ (n & 7);
      gload_lds16(Wout + (size_t)n * 512 + ss * 8, &Wls[0][idx * 8]);
    }
  }

  // ---- build A panel in registers: 2 m-frags x 16 k-frags, bf16x8 each ----
  bf16x8 afr[32];
#pragma unroll
  for (int mf = 0; mf < 2; mf++) {
    int rr = wm + mf * 16 + (lane & 15);
    int t = t0 + (rr >> 6), u = rr & 63;
    const float* ep = encp + ((size_t)(b * 128 + t)) * 512;
    const float* dp = decp + ((size_t)(b * 64 + u)) * 512;
#pragma unroll
    for (int kf = 0; kf < 16; kf++) {
      int k0 = kf * 32 + ((lane >> 4) << 3);
      bf16x8 v;
#pragma unroll
      for (int j = 0; j < 8; j++) {
        float x = ep[k0 + j] + dp[k0 + j];
        float e = __expf(x + x);
        v[j] = (short)f2bf(1.f - 2.f / (e + 1.f));
      }
      afr[mf * 16 + kf] = v;
    }
  }

  f32x4 acc[2][4];
#pragma unroll
  for (int mf = 0; mf < 2; mf++)
#pragma unroll
    for (int nf = 0; nf < 4; nf++) acc[mf][nf] = (f32x4){0.f, 0.f, 0.f, 0.f};

  // ---- main loop: 16 n-tiles x 8 k-chunks, depth-1 prefetch ----
  for (int c = 0; c < 128; c++) {
    int nt = c >> 3, kc = c & 7;
    __syncthreads();                    // drains vmcnt(0): chunk c is in LDS
    if (c < 127) {
      int c1i = c + 1;
      int nn0 = (c1i >> 3) << 7;
      int kb = (c1i & 7) * 64;
      unsigned short* dst = Wls[c1i & 1];
#pragma unroll
      for (int q = 0; q < 2; q++) {
        int idx = tid + q * 512;
        int n = idx >> 3, sl = idx & 7;
        int ss = sl ^ (n & 7);
        gload_lds16(Wout + (size_t)(nn0 + n) * 512 + kb + ss * 8, dst + idx * 8);
      }
    }
    const unsigned short* Wb = Wls[c & 1];
#pragma unroll
    for (int ks = 0; ks < 2; ks++) {
      bf16x8 bfr[4];
#pragma unroll
      for (int nf = 0; nf < 4; nf++) {
        int n = wn + nf * 16 + (lane & 15);
        int slot = ks * 4 + (lane >> 4);
        int phys = slot ^ (n & 7);
        bfr[nf] = *(const bf16x8*)(Wb + n * 64 + phys * 8);
      }
      int kf = kc * 2 + ks;
#pragma unroll
      for (int mf = 0; mf < 2; mf++)
#pragma unroll
        for (int nf = 0; nf < 4; nf++)
          acc[mf][nf] = __builtin_amdgcn_mfma_f32_16x16x32_bf16(afr[mf * 16 + kf], bfr[nf],
                                                                acc[mf][nf], 0, 0, 0);
    }
    if (kc == 7) {                      // epilogue for this n-tile
      int n0 = nt << 7;
#pragma unroll
      for (int mf = 0; mf < 2; mf++) {
        int rb = wm + mf * 16 + ((lane >> 4) << 2);
#pragma unroll
        for (int nf = 0; nf < 4; nf++) {
          int o = n0 + wn + nf * 16 + (lane & 15);
          float bb = bout[o];
#pragma unroll
          for (int q = 0; q < 4; q++) {
            int rr = rb + q;
            int t = t0 + (rr >> 6), u = rr & 63;
            __builtin_nontemporal_store(acc[mf][nf][q] + bb,
                &out[(((size_t)(b * 128 + t)) * 64 + u) * 2048 + o]);
          }
          acc[mf][nf] = (f32x4){0.f, 0.f, 0.f, 0.f};
        }
      }
    }
  }
}

// ---------------- launch ----------------
extern "C" void kernel_launch(void* const* d_in, const int* in_sizes, int n_in,
                              void* d_out, int out_size, void* d_ws, size_t ws_size,
                              hipStream_t stream) {
  const float* hs   = (const float*)d_in[0];
  const int*   ys   = (const int*)d_in[1];
  const float* emb  = (const float*)d_in[2];
  const float* Wih0 = (const float*)d_in[3];
  const float* Whh0 = (const float*)d_in[4];
  const float* bih0 = (const float*)d_in[5];
  const float* bhh0 = (const float*)d_in[6];
  const float* Wih1 = (const float*)d_in[7];
  const float* Whh1 = (const float*)d_in[8];
  const float* bih1 = (const float*)d_in[9];
  const float* bhh1 = (const float*)d_in[10];
  const float* Wenc = (const float*)d_in[11];
  const float* benc = (const float*)d_in[12];
  const float* Wdec = (const float*)d_in[13];
  const float* Wout = (const float*)d_in[14];
  const float* bout = (const float*)d_in[15];

  char* ws = (char*)d_ws;
  float*          eys   = (float*)(ws + 0);            // 256x512 f32        = 524,288
  float*          X0    = (float*)(ws + 524288);       // 256x4096 f32       = 4,194,304
  float*          encp  = (float*)(ws + 4718592);      // 512x512 f32        = 1,048,576
  float*          decp  = (float*)(ws + 5767168);      // 256x512 f32        = 524,288
  float*          h0h   = (float*)(ws + 6291456);      // 65x4096 f32        = 1,064,960
  float*          h1h   = (float*)(ws + 7356416);      // 65x4096 f32        = 1,064,960
  float*          hdec  = (float*)(ws + 8421376);      // 256x1024 f32       = 1,048,576
  int*            bar   = (int*)(ws + 9469952);        // grid barrier counter
  unsigned short* Whh0b = (unsigned short*)(ws + 9502720);   // 4M bf16      = 8,388,608
  unsigned short* Wih1b = (unsigned short*)(ws + 17891328);  // 4M bf16      = 8,388,608
  unsigned short* Whh1b = (unsigned short*)(ws + 26279936);  // 4M bf16      = 8,388,608
  unsigned short* Woutb = (unsigned short*)(ws + 34668544);  // 1M bf16      = 2,097,152
  float*          out   = (float*)d_out;                     // total ws = 36,765,696 B

  // weight conversion (bf16 for LSTM recurrent mats + Wout for global_load_lds)
  k_cvt<<<6656, 256, 0, stream>>>(Whh0, Wih1, Whh1, Wout, Whh0b, Wih1b, Whh1b, Woutb);
  k_prep<<<64, 256, 0, stream>>>(ys, emb, eys, h0h, h1h, bar);
  // X0 = eys @ Wih0^T + bih0 + bhh0   (M=256, N=4096, K=512)
  k_gemm_bias<<<256, 256, 0, stream>>>(eys, Wih0, bih0, bhh0, X0, 256, 4096, 512);
  // encp = hs @ Wenc^T + benc         (M=512, N=512, K=512)
  k_gemm_bias<<<64, 256, 0, stream>>>(hs, Wenc, benc, nullptr, encp, 512, 512, 512);
  // fused LSTM: 65 pipelined phases, one persistent kernel with grid barrier
  k_lstm_fused<<<256, 512, 0, stream>>>(X0, h0h, h1h, hdec,
                                        Whh0b, Wih1b, Whh1b, bih1, bhh1, bar);
  // decp = hdec @ Wdec^T              (M=256, N=512, K=1024)
  k_gemm_bias<<<32, 256, 0, stream>>>(hdec, Wdec, nullptr, nullptr, decp, 256, 512, 1024);
  // joint
  k_joint<<<256, 512, 0, stream>>>(encp, decp, Woutb, bout, out);
}

// Round 5
// 1137.310 us; speedup vs baseline: 4.1732x; 4.1732x over previous
//
#include <hip/hip_runtime.h>
#include <stdint.h>

typedef short bf16x8 __attribute__((ext_vector_type(8)));
typedef float f32x4 __attribute__((ext_vector_type(4)));

__device__ __forceinline__ unsigned short f2bf(float f) {
  union { float f; unsigned int i; } v; v.f = f;
  unsigned int r = v.i + 0x7FFF + ((v.i >> 16) & 1);
  return (unsigned short)(r >> 16);
}
__device__ __forceinline__ float bfu2f(unsigned short u) {
  union { unsigned int i; float f; } v; v.i = ((unsigned int)u) << 16; return v.f;
}
__device__ __forceinline__ void gload_lds16(const void* g, void* l) {
  __builtin_amdgcn_global_load_lds(
      (const __attribute__((address_space(1))) unsigned int*)g,
      (__attribute__((address_space(3))) unsigned int*)l,
      16, 0, 0);
}

// ---------------- convert f32 weights -> bf16 (Whh0, Wih1, Whh1, Wout) ----------------
__global__ __launch_bounds__(256) void k_cvt(const float* __restrict__ s0, const float* __restrict__ s1,
                                             const float* __restrict__ s2, const float* __restrict__ s3,
                                             unsigned short* __restrict__ d0, unsigned short* __restrict__ d1,
                                             unsigned short* __restrict__ d2, unsigned short* __restrict__ d3) {
  int j = blockIdx.x * 256 + threadIdx.x;   // 6656*256 = 1,703,936 vec8 jobs exactly
  const float* s; unsigned short* d; int o;
  if (j < 524288)       { s = s0; d = d0; o = j; }
  else if (j < 1048576) { s = s1; d = d1; o = j - 524288; }
  else if (j < 1572864) { s = s2; d = d2; o = j - 1048576; }
  else                  { s = s3; d = d3; o = j - 1572864; }
  size_t off = (size_t)o * 8;
  f32x4 v0 = *(const f32x4*)(s + off);
  f32x4 v1 = *(const f32x4*)(s + off + 4);
  bf16x8 r;
#pragma unroll
  for (int k = 0; k < 4; k++) { r[k] = (short)f2bf(v0[k]); r[4 + k] = (short)f2bf(v1[k]); }
  *(bf16x8*)(d + off) = r;
}

// ---------------- prep: embedding gather (f32) + zero state + zero barrier counters ----------------
__global__ __launch_bounds__(256) void k_prep(const int* __restrict__ ys,
                                              const float* __restrict__ embed,
                                              float* __restrict__ eys,
                                              float* __restrict__ h0h, float* __restrict__ h1h,
                                              int* __restrict__ bar) {
  int idx = blockIdx.x * 256 + threadIdx.x;   // 16384 threads
  int row = idx >> 6;
  int e = (idx & 63) * 8;
  int y = ys[row];
  f32x4 v0 = {0.f, 0.f, 0.f, 0.f}, v1 = {0.f, 0.f, 0.f, 0.f};
  if (y != 0) {
    v0 = *(const f32x4*)(embed + (size_t)y * 512 + e);
    v1 = *(const f32x4*)(embed + (size_t)y * 512 + e + 4);
  }
  *(f32x4*)(eys + (size_t)row * 512 + e) = v0;
  *(f32x4*)(eys + (size_t)row * 512 + e + 4) = v1;
  if (idx < 4096) { h0h[idx] = 0.f; h1h[idx] = 0.f; }
  if (idx < 8) bar[idx << 10] = 0;            // 8 group counters, 4KB apart
  if (idx == 8) bar[(7 << 10) + 512] = 0;     // root counter
}

// -------- generic small GEMM: C(f32 MxN) = A(f32 MxK) @ W(f32 NxK)^T + b1 + b2 --------
__global__ __launch_bounds__(256) void k_gemm_bias(const float* __restrict__ A,
                                                   const float* __restrict__ W,
                                                   const float* __restrict__ b1,
                                                   const float* __restrict__ b2,
                                                   float* __restrict__ C,
                                                   int M, int N, int K) {
  __shared__ unsigned short Als[64][40];
  __shared__ unsigned short Wls[64][40];
  int tid = threadIdx.x;
  int lane = tid & 63, wid = tid >> 6;
  int mtiles = M >> 6;
  int mt = blockIdx.x % mtiles, nt = blockIdx.x / mtiles;
  int srow = tid >> 2, sseg = tid & 3;
  f32x4 acc[4];
#pragma unroll
  for (int nf = 0; nf < 4; nf++) acc[nf] = (f32x4){0.f, 0.f, 0.f, 0.f};

  for (int kc = 0; kc < K; kc += 32) {
    const float* ap = A + (size_t)(mt * 64 + srow) * K + kc + sseg * 8;
    const float* wp = W + (size_t)(nt * 64 + srow) * K + kc + sseg * 8;
    f32x4 a0 = *(const f32x4*)ap, a1 = *(const f32x4*)(ap + 4);
    f32x4 w0 = *(const f32x4*)wp, w1 = *(const f32x4*)(wp + 4);
    bf16x8 av, wv;
#pragma unroll
    for (int k = 0; k < 4; k++) {
      av[k] = (short)f2bf(a0[k]); av[4 + k] = (short)f2bf(a1[k]);
      wv[k] = (short)f2bf(w0[k]); wv[4 + k] = (short)f2bf(w1[k]);
    }
    __syncthreads();
    *(bf16x8*)(&Als[srow][sseg * 8]) = av;
    *(bf16x8*)(&Wls[srow][sseg * 8]) = wv;
    __syncthreads();
    bf16x8 af = *(const bf16x8*)(&Als[wid * 16 + (lane & 15)][(lane >> 4) * 8]);
#pragma unroll
    for (int nf = 0; nf < 4; nf++) {
      bf16x8 bf = *(const bf16x8*)(&Wls[nf * 16 + (lane & 15)][(lane >> 4) * 8]);
      acc[nf] = __builtin_amdgcn_mfma_f32_16x16x32_bf16(af, bf, acc[nf], 0, 0, 0);
    }
  }
  int rloc = (lane >> 4) * 4;
  int col0 = lane & 15;
#pragma unroll
  for (int nf = 0; nf < 4; nf++) {
    int n = nt * 64 + nf * 16 + col0;
    float bias = 0.f;
    if (b1) bias += b1[n];
    if (b2) bias += b2[n];
#pragma unroll
    for (int r = 0; r < 4; r++) {
      int m = mt * 64 + wid * 16 + rloc + r;
      C[(size_t)m * N + n] = acc[nf][r] + bias;
    }
  }
}

// ---------------- fused LSTM: 65 pipelined phases, one persistent kernel ----------------
// 256 blocks x 512 threads. Blocks 0..127: layer0 (8 ch each). 128..255: layer1.
// Weights held PACKED (bf16) in registers; unpack on use. No threadfence anywhere:
// h-state moves via agent-scope relaxed atomics (sc1, coherence-point), barrier is a
// fence-free hierarchical counter tree (8 leaf pages + 1 root).
__global__ __launch_bounds__(512, 2) void k_lstm_fused(
    const float* __restrict__ X0,            // (B,U,4096)  eys@Wih0^T + bih0 + bhh0
    float* __restrict__ h0h,                 // (65,B,1024)
    float* __restrict__ h1h,                 // (65,B,1024)
    float* __restrict__ hdec,                // (B,U,1024) f32
    const unsigned short* __restrict__ W_hh0,
    const unsigned short* __restrict__ W_ih1,
    const unsigned short* __restrict__ W_hh1,
    const float* __restrict__ b_ih1,
    const float* __restrict__ b_hh1,
    int* __restrict__ bar) {
  __shared__ float xs[2 * 4096];       // 32 KB
  __shared__ float red[16][32][4];     // 8 KB
  __shared__ float gsum[32][4];
  int tid = threadIdx.x;
  bool is1 = blockIdx.x >= 128;
  int base = (blockIdx.x & 127) * 8;
  int grp = blockIdx.x >> 5;           // 8 groups of 32 blocks
  int s = tid >> 5;          // 0..15  K-segment
  int r = tid & 31;          // 0..31  row = gate*8 + ch
  int g = r >> 3, cl = r & 7;
  int wrow = g * 1024 + base + cl;

  // ---- preload weights PACKED bf16 into registers (held across all phases) ----
  bf16x8 wv[16];             // layer0 uses [0..7] (32 VGPR), layer1 all 16 (64 VGPR)
  const float* xb;
  if (!is1) {
    const unsigned short* wptr = W_hh0 + (size_t)wrow * 1024 + s * 64;
#pragma unroll
    for (int i = 0; i < 8; i++) wv[i] = *(const bf16x8*)(wptr + i * 8);
    xb = xs + s * 64;
  } else {
    const unsigned short* wptr = (s < 8) ? (W_ih1 + (size_t)wrow * 1024 + s * 128)
                                         : (W_hh1 + (size_t)wrow * 1024 + (s - 8) * 128);
#pragma unroll
    for (int i = 0; i < 16; i++) wv[i] = *(const bf16x8*)(wptr + i * 8);
    xb = (s < 8) ? (xs + s * 128) : (xs + 4096 + (s - 8) * 128);
  }

  // per-thread persistent cell state (tid<32: ch = base + (tid>>2), b = tid&3)
  float creg = 0.f;
  float bsum0 = 0.f, bsum1 = 0.f, bsum2 = 0.f, bsum3 = 0.f;
  if (is1 && tid < 32) {
    int ch = base + (tid >> 2);
    bsum0 = b_ih1[ch] + b_hh1[ch];
    bsum1 = b_ih1[1024 + ch] + b_hh1[1024 + ch];
    bsum2 = b_ih1[2048 + ch] + b_hh1[2048 + ch];
    bsum3 = b_ih1[3072 + ch] + b_hh1[3072 + ch];
  }

  for (int p = 0; p < 65; p++) {
    bool active = is1 ? (p >= 1) : (p < 64);
    if (active) {
      // ---- stage x vectors into LDS via coherence-point (sc1) loads ----
      {
        const unsigned long long* h0p = (const unsigned long long*)(h0h + (size_t)p * 4096);
        for (int i = tid; i < 2048; i += 512) {
          unsigned long long v = __hip_atomic_load(h0p + i, __ATOMIC_RELAXED, __HIP_MEMORY_SCOPE_AGENT);
          *(unsigned long long*)&xs[i * 2] = v;
        }
        if (is1) {
          const unsigned long long* h1p = (const unsigned long long*)(h1h + (size_t)(p - 1) * 4096);
          for (int i = tid; i < 2048; i += 512) {
            unsigned long long v = __hip_atomic_load(h1p + i, __ATOMIC_RELAXED, __HIP_MEMORY_SCOPE_AGENT);
            *(unsigned long long*)&xs[4096 + i * 2] = v;
          }
        }
      }
      __syncthreads();

      // ---- GEMV partials (unpack packed weights on use) ----
      float a0 = 0.f, a1 = 0.f, a2 = 0.f, a3 = 0.f;
      if (!is1) {
#pragma unroll
        for (int i = 0; i < 8; i++) {
          bf16x8 w = wv[i];
          f32x4 x00 = *(const f32x4*)(xb + i * 8);
          f32x4 x01 = *(const f32x4*)(xb + i * 8 + 4);
          f32x4 x10 = *(const f32x4*)(xb + 1024 + i * 8);
          f32x4 x11 = *(const f32x4*)(xb + 1024 + i * 8 + 4);
          f32x4 x20 = *(const f32x4*)(xb + 2048 + i * 8);
          f32x4 x21 = *(const f32x4*)(xb + 2048 + i * 8 + 4);
          f32x4 x30 = *(const f32x4*)(xb + 3072 + i * 8);
          f32x4 x31 = *(const f32x4*)(xb + 3072 + i * 8 + 4);
#pragma unroll
          for (int j = 0; j < 4; j++) {
            float wf = bfu2f((unsigned short)w[j]);
            a0 += wf * x00[j]; a1 += wf * x10[j]; a2 += wf * x20[j]; a3 += wf * x30[j];
          }
#pragma unroll
          for (int j = 0; j < 4; j++) {
            float wf = bfu2f((unsigned short)w[4 + j]);
            a0 += wf * x01[j]; a1 += wf * x11[j]; a2 += wf * x21[j]; a3 += wf * x31[j];
          }
        }
      } else {
#pragma unroll
        for (int i = 0; i < 16; i++) {
          bf16x8 w = wv[i];
          f32x4 x00 = *(const f32x4*)(xb + i * 8);
          f32x4 x01 = *(const f32x4*)(xb + i * 8 + 4);
          f32x4 x10 = *(const f32x4*)(xb + 1024 + i * 8);
          f32x4 x11 = *(const f32x4*)(xb + 1024 + i * 8 + 4);
          f32x4 x20 = *(const f32x4*)(xb + 2048 + i * 8);
          f32x4 x21 = *(const f32x4*)(xb + 2048 + i * 8 + 4);
          f32x4 x30 = *(const f32x4*)(xb + 3072 + i * 8);
          f32x4 x31 = *(const f32x4*)(xb + 3072 + i * 8 + 4);
#pragma unroll
          for (int j = 0; j < 4; j++) {
            float wf = bfu2f((unsigned short)w[j]);
            a0 += wf * x00[j]; a1 += wf * x10[j]; a2 += wf * x20[j]; a3 += wf * x30[j];
          }
#pragma unroll
          for (int j = 0; j < 4; j++) {
            float wf = bfu2f((unsigned short)w[4 + j]);
            a0 += wf * x01[j]; a1 += wf * x11[j]; a2 += wf * x21[j]; a3 += wf * x31[j];
          }
        }
      }
      *(f32x4*)&red[s][r][0] = (f32x4){a0, a1, a2, a3};
      __syncthreads();
      if (tid < 128) {
        int rr = tid >> 2, b = tid & 3;
        float sum = 0.f;
#pragma unroll
        for (int ss = 0; ss < 16; ss++) sum += red[ss][rr][b];
        gsum[rr][b] = sum;
      }
      __syncthreads();
      if (tid < 32) {
        int cl2 = tid >> 2, b = tid & 3;
        int ch = base + cl2;
        float gi = gsum[cl2][b], gf = gsum[8 + cl2][b];
        float gg = gsum[16 + cl2][b], go = gsum[24 + cl2][b];
        if (!is1) {
          const float* x0p = X0 + ((size_t)(b * 64 + p)) * 4096;
          gi += x0p[ch]; gf += x0p[1024 + ch]; gg += x0p[2048 + ch]; go += x0p[3072 + ch];
        } else {
          gi += bsum0; gf += bsum1; gg += bsum2; go += bsum3;
        }
        float ii = 1.f / (1.f + __expf(-gi));
        float ff = 1.f / (1.f + __expf(-gf));
        float oo = 1.f / (1.f + __expf(-go));
        float cn = ff * creg + ii * tanhf(gg);
        creg = cn;
        float hn = oo * tanhf(cn);
        if (!is1) {
          __hip_atomic_store(&h0h[(size_t)(p + 1) * 4096 + b * 1024 + ch], hn,
                             __ATOMIC_RELAXED, __HIP_MEMORY_SCOPE_AGENT);
        } else {
          __hip_atomic_store(&h1h[(size_t)p * 4096 + b * 1024 + ch], hn,
                             __ATOMIC_RELAXED, __HIP_MEMORY_SCOPE_AGENT);
          hdec[((size_t)(b * 64 + (p - 1))) * 1024 + ch] = hn;  // consumed after kernel end
        }
      }
    }
    // ---- fence-free hierarchical grid barrier ----
    if (p < 64) {
      asm volatile("s_waitcnt vmcnt(0)" ::: "memory");  // my sc1 h-stores are at coherence point
      __syncthreads();                                  // ...for ALL lanes of this block
      if (tid == 0) {
        __hip_atomic_fetch_add(&bar[grp << 10], 1, __ATOMIC_RELAXED, __HIP_MEMORY_SCOPE_AGENT);
        if ((blockIdx.x & 31) == 0) {
          int tgt = 32 * (p + 1);
          while (__hip_atomic_load(&bar[grp << 10], __ATOMIC_RELAXED, __HIP_MEMORY_SCOPE_AGENT) < tgt)
            __builtin_amdgcn_s_sleep(1);
          __hip_atomic_fetch_add(&bar[(7 << 10) + 512], 1, __ATOMIC_RELAXED, __HIP_MEMORY_SCOPE_AGENT);
        }
        int rtgt = 8 * (p + 1);
        while (__hip_atomic_load(&bar[(7 << 10) + 512], __ATOMIC_RELAXED, __HIP_MEMORY_SCOPE_AGENT) < rtgt)
          __builtin_amdgcn_s_sleep(1);
      }
      __syncthreads();
    }
  }
}

// ---------------- joint: out[b,t,u,:] = tanh(encp[b,t,:]+decp[b,u,:]) @ Wout^T + bout ----
// 256 blocks x 512 threads; z-panel in regs; NONTEMPORAL f32 output stores.
__global__ __launch_bounds__(512) void k_joint(const float* __restrict__ encp,   // (B,T,512)
                                               const float* __restrict__ decp,   // (B,U,512)
                                               const unsigned short* __restrict__ Wout, // (2048,512) bf16
                                               const float* __restrict__ bout,   // (2048) f32
                                               float* __restrict__ out) {        // (B,T,U,2048) f32
  __shared__ unsigned short Wls[2][8192];   // 2 x 16KB: 128 n-rows x 64 k (swizzled)
  int tid = threadIdx.x;
  int lane = tid & 63, wid = tid >> 6;      // 8 waves
  int bidx = blockIdx.x;
  int b = bidx >> 6, tloc = bidx & 63;
  int t0 = tloc * 2;
  int wm = (wid >> 1) * 32;                 // 4 m-waves x 32 rows
  int wn = (wid & 1) * 64;                  // 2 n-waves x 64 cols

  // ---- prologue: issue stage of chunk 0 (overlaps with A-build) ----
  {
#pragma unroll
    for (int q = 0; q < 2; q++) {
      int idx = tid + q * 512;
      int n = idx >> 3, sl = idx & 7;
      int ss = sl ^ (n & 7);
      gload_lds16(Wout + (size_t)n * 512 + ss * 8, &Wls[0][idx * 8]);
    }
  }

  // ---- build A panel in registers: 2 m-frags x 16 k-frags, bf16x8 each ----
  bf16x8 afr[32];
#pragma unroll
  for (int mf = 0; mf < 2; mf++) {
    int rr = wm + mf * 16 + (lane & 15);
    int t = t0 + (rr >> 6), u = rr & 63;
    const float* ep = encp + ((size_t)(b * 128 + t)) * 512;
    const float* dp = decp + ((size_t)(b * 64 + u)) * 512;
#pragma unroll
    for (int kf = 0; kf < 16; kf++) {
      int k0 = kf * 32 + ((lane >> 4) << 3);
      bf16x8 v;
#pragma unroll
      for (int j = 0; j < 8; j++) {
        float x = ep[k0 + j] + dp[k0 + j];
        float e = __expf(x + x);
        v[j] = (short)f2bf(1.f - 2.f / (e + 1.f));
      }
      afr[mf * 16 + kf] = v;
    }
  }

  f32x4 acc[2][4];
#pragma unroll
  for (int mf = 0; mf < 2; mf++)
#pragma unroll
    for (int nf = 0; nf < 4; nf++) acc[mf][nf] = (f32x4){0.f, 0.f, 0.f, 0.f};

  // ---- main loop: 16 n-tiles x 8 k-chunks, depth-1 prefetch ----
  for (int c = 0; c < 128; c++) {
    int nt = c >> 3, kc = c & 7;
    __syncthreads();                    // drains vmcnt(0): chunk c is in LDS
    if (c < 127) {
      int c1i = c + 1;
      int nn0 = (c1i >> 3) << 7;
      int kb = (c1i & 7) * 64;
      unsigned short* dst = Wls[c1i & 1];
#pragma unroll
      for (int q = 0; q < 2; q++) {
        int idx = tid + q * 512;
        int n = idx >> 3, sl = idx & 7;
        int ss = sl ^ (n & 7);
        gload_lds16(Wout + (size_t)(nn0 + n) * 512 + kb + ss * 8, dst + idx * 8);
      }
    }
    const unsigned short* Wb = Wls[c & 1];
#pragma unroll
    for (int ks = 0; ks < 2; ks++) {
      bf16x8 bfr[4];
#pragma unroll
      for (int nf = 0; nf < 4; nf++) {
        int n = wn + nf * 16 + (lane & 15);
        int slot = ks * 4 + (lane >> 4);
        int phys = slot ^ (n & 7);
        bfr[nf] = *(const bf16x8*)(Wb + n * 64 + phys * 8);
      }
      int kf = kc * 2 + ks;
#pragma unroll
      for (int mf = 0; mf < 2; mf++)
#pragma unroll
        for (int nf = 0; nf < 4; nf++)
          acc[mf][nf] = __builtin_amdgcn_mfma_f32_16x16x32_bf16(afr[mf * 16 + kf], bfr[nf],
                                                                acc[mf][nf], 0, 0, 0);
    }
    if (kc == 7) {                      // epilogue for this n-tile
      int n0 = nt << 7;
#pragma unroll
      for (int mf = 0; mf < 2; mf++) {
        int rb = wm + mf * 16 + ((lane >> 4) << 2);
#pragma unroll
        for (int nf = 0; nf < 4; nf++) {
          int o = n0 + wn + nf * 16 + (lane & 15);
          float bb = bout[o];
#pragma unroll
          for (int q = 0; q < 4; q++) {
            int rr = rb + q;
            int t = t0 + (rr >> 6), u = rr & 63;
            __builtin_nontemporal_store(acc[mf][nf][q] + bb,
                &out[(((size_t)(b * 128 + t)) * 64 + u) * 2048 + o]);
          }
          acc[mf][nf] = (f32x4){0.f, 0.f, 0.f, 0.f};
        }
      }
    }
  }
}

// ---------------- launch ----------------
extern "C" void kernel_launch(void* const* d_in, const int* in_sizes, int n_in,
                              void* d_out, int out_size, void* d_ws, size_t ws_size,
                              hipStream_t stream) {
  const float* hs   = (const float*)d_in[0];
  const int*   ys   = (const int*)d_in[1];
  const float* emb  = (const float*)d_in[2];
  const float* Wih0 = (const float*)d_in[3];
  const float* Whh0 = (const float*)d_in[4];
  const float* bih0 = (const float*)d_in[5];
  const float* bhh0 = (const float*)d_in[6];
  const float* Wih1 = (const float*)d_in[7];
  const float* Whh1 = (const float*)d_in[8];
  const float* bih1 = (const float*)d_in[9];
  const float* bhh1 = (const float*)d_in[10];
  const float* Wenc = (const float*)d_in[11];
  const float* benc = (const float*)d_in[12];
  const float* Wdec = (const float*)d_in[13];
  const float* Wout = (const float*)d_in[14];
  const float* bout = (const float*)d_in[15];

  char* ws = (char*)d_ws;
  float*          eys   = (float*)(ws + 0);            // 256x512 f32        = 524,288
  float*          X0    = (float*)(ws + 524288);       // 256x4096 f32       = 4,194,304
  float*          encp  = (float*)(ws + 4718592);      // 512x512 f32        = 1,048,576
  float*          decp  = (float*)(ws + 5767168);      // 256x512 f32        = 524,288
  float*          h0h   = (float*)(ws + 6291456);      // 65x4096 f32        = 1,064,960
  float*          h1h   = (float*)(ws + 7356416);      // 65x4096 f32        = 1,064,960
  float*          hdec  = (float*)(ws + 8421376);      // 256x1024 f32       = 1,048,576
  int*            bar   = (int*)(ws + 9469952);        // 8 pages of counters = 32,768
  unsigned short* Whh0b = (unsigned short*)(ws + 9502720);   // 4M bf16      = 8,388,608
  unsigned short* Wih1b = (unsigned short*)(ws + 17891328);  // 4M bf16      = 8,388,608
  unsigned short* Whh1b = (unsigned short*)(ws + 26279936);  // 4M bf16      = 8,388,608
  unsigned short* Woutb = (unsigned short*)(ws + 34668544);  // 1M bf16      = 2,097,152
  float*          out   = (float*)d_out;                     // total ws = 36,765,696 B

  // weight conversion (bf16 for LSTM recurrent mats + Wout for global_load_lds)
  k_cvt<<<6656, 256, 0, stream>>>(Whh0, Wih1, Whh1, Wout, Whh0b, Wih1b, Whh1b, Woutb);
  k_prep<<<64, 256, 0, stream>>>(ys, emb, eys, h0h, h1h, bar);
  // X0 = eys @ Wih0^T + bih0 + bhh0   (M=256, N=4096, K=512)
  k_gemm_bias<<<256, 256, 0, stream>>>(eys, Wih0, bih0, bhh0, X0, 256, 4096, 512);
  // encp = hs @ Wenc^T + benc         (M=512, N=512, K=512)
  k_gemm_bias<<<64, 256, 0, stream>>>(hs, Wenc, benc, nullptr, encp, 512, 512, 512);
  // fused LSTM: 65 pipelined phases, one persistent kernel, fence-free barrier
  k_lstm_fused<<<256, 512, 0, stream>>>(X0, h0h, h1h, hdec,
                                        Whh0b, Wih1b, Whh1b, bih1, bhh1, bar);
  // decp = hdec @ Wdec^T              (M=256, N=512, K=1024)
  k_gemm_bias<<<32, 256, 0, stream>>>(hdec, Wdec, nullptr, nullptr, decp, 256, 512, 1024);
  // joint
  k_joint<<<256, 512, 0, stream>>>(encp, decp, Woutb, bout, out);
}

// Round 6
// 948.095 us; speedup vs baseline: 5.0061x; 1.1996x over previous
//
#include <hip/hip_runtime.h>
#include <stdint.h>

typedef short bf16x8 __attribute__((ext_vector_type(8)));
typedef float f32x4 __attribute__((ext_vector_type(4)));

__device__ __forceinline__ unsigned short f2bf(float f) {
  union { float f; unsigned int i; } v; v.f = f;
  unsigned int r = v.i + 0x7FFF + ((v.i >> 16) & 1);
  return (unsigned short)(r >> 16);
}
__device__ __forceinline__ float bfu2f(unsigned short u) {
  union { unsigned int i; float f; } v; v.i = ((unsigned int)u) << 16; return v.f;
}
__device__ __forceinline__ void gload_lds16(const void* g, void* l) {
  __builtin_amdgcn_global_load_lds(
      (const __attribute__((address_space(1))) unsigned int*)g,
      (__attribute__((address_space(3))) unsigned int*)l,
      16, 0, 0);
}

// ---------------- convert f32 weights -> bf16 (Whh0, Wih1, Whh1, Wout) ----------------
__global__ __launch_bounds__(256) void k_cvt(const float* __restrict__ s0, const float* __restrict__ s1,
                                             const float* __restrict__ s2, const float* __restrict__ s3,
                                             unsigned short* __restrict__ d0, unsigned short* __restrict__ d1,
                                             unsigned short* __restrict__ d2, unsigned short* __restrict__ d3) {
  int j = blockIdx.x * 256 + threadIdx.x;   // 6656*256 = 1,703,936 vec8 jobs exactly
  const float* s; unsigned short* d; int o;
  if (j < 524288)       { s = s0; d = d0; o = j; }
  else if (j < 1048576) { s = s1; d = d1; o = j - 524288; }
  else if (j < 1572864) { s = s2; d = d2; o = j - 1048576; }
  else                  { s = s3; d = d3; o = j - 1572864; }
  size_t off = (size_t)o * 8;
  f32x4 v0 = *(const f32x4*)(s + off);
  f32x4 v1 = *(const f32x4*)(s + off + 4);
  bf16x8 r;
#pragma unroll
  for (int k = 0; k < 4; k++) { r[k] = (short)f2bf(v0[k]); r[4 + k] = (short)f2bf(v1[k]); }
  *(bf16x8*)(d + off) = r;
}

// ---------------- prep: embedding gather (f32) + zero state + zero dataflow counters ------
__global__ __launch_bounds__(256) void k_prep(const int* __restrict__ ys,
                                              const float* __restrict__ embed,
                                              float* __restrict__ eys,
                                              float* __restrict__ h0h, float* __restrict__ h1h,
                                              int* __restrict__ cnt) {
  int idx = blockIdx.x * 256 + threadIdx.x;   // 16384 threads
  int row = idx >> 6;
  int e = (idx & 63) * 8;
  int y = ys[row];
  f32x4 v0 = {0.f, 0.f, 0.f, 0.f}, v1 = {0.f, 0.f, 0.f, 0.f};
  if (y != 0) {
    v0 = *(const f32x4*)(embed + (size_t)y * 512 + e);
    v1 = *(const f32x4*)(embed + (size_t)y * 512 + e + 4);
  }
  *(f32x4*)(eys + (size_t)row * 512 + e) = v0;
  *(f32x4*)(eys + (size_t)row * 512 + e + 4) = v1;
  if (idx < 4096) { h0h[idx] = 0.f; h1h[idx] = 0.f; }
  if (idx < 4160) cnt[idx] = 0;               // 2 x 65 counters, stride 32 ints
}

// -------- generic small GEMM: C(f32 MxN) = A(f32 MxK) @ W(f32 NxK)^T + b1 + b2 --------
__global__ __launch_bounds__(256) void k_gemm_bias(const float* __restrict__ A,
                                                   const float* __restrict__ W,
                                                   const float* __restrict__ b1,
                                                   const float* __restrict__ b2,
                                                   float* __restrict__ C,
                                                   int M, int N, int K) {
  __shared__ unsigned short Als[64][40];
  __shared__ unsigned short Wls[64][40];
  int tid = threadIdx.x;
  int lane = tid & 63, wid = tid >> 6;
  int mtiles = M >> 6;
  int mt = blockIdx.x % mtiles, nt = blockIdx.x / mtiles;
  int srow = tid >> 2, sseg = tid & 3;
  f32x4 acc[4];
#pragma unroll
  for (int nf = 0; nf < 4; nf++) acc[nf] = (f32x4){0.f, 0.f, 0.f, 0.f};

  for (int kc = 0; kc < K; kc += 32) {
    const float* ap = A + (size_t)(mt * 64 + srow) * K + kc + sseg * 8;
    const float* wp = W + (size_t)(nt * 64 + srow) * K + kc + sseg * 8;
    f32x4 a0 = *(const f32x4*)ap, a1 = *(const f32x4*)(ap + 4);
    f32x4 w0 = *(const f32x4*)wp, w1 = *(const f32x4*)(wp + 4);
    bf16x8 av, wv;
#pragma unroll
    for (int k = 0; k < 4; k++) {
      av[k] = (short)f2bf(a0[k]); av[4 + k] = (short)f2bf(a1[k]);
      wv[k] = (short)f2bf(w0[k]); wv[4 + k] = (short)f2bf(w1[k]);
    }
    __syncthreads();
    *(bf16x8*)(&Als[srow][sseg * 8]) = av;
    *(bf16x8*)(&Wls[srow][sseg * 8]) = wv;
    __syncthreads();
    bf16x8 af = *(const bf16x8*)(&Als[wid * 16 + (lane & 15)][(lane >> 4) * 8]);
#pragma unroll
    for (int nf = 0; nf < 4; nf++) {
      bf16x8 bf = *(const bf16x8*)(&Wls[nf * 16 + (lane & 15)][(lane >> 4) * 8]);
      acc[nf] = __builtin_amdgcn_mfma_f32_16x16x32_bf16(af, bf, acc[nf], 0, 0, 0);
    }
  }
  int rloc = (lane >> 4) * 4;
  int col0 = lane & 15;
#pragma unroll
  for (int nf = 0; nf < 4; nf++) {
    int n = nt * 64 + nf * 16 + col0;
    float bias = 0.f;
    if (b1) bias += b1[n];
    if (b2) bias += b2[n];
#pragma unroll
    for (int r = 0; r < 4; r++) {
      int m = mt * 64 + wid * 16 + rloc + r;
      C[(size_t)m * N + n] = acc[nf][r] + bias;
    }
  }
}

// ---------------- fused LSTM: MFMA recurrent GEMV + per-step dataflow counters ----------
// 256 blocks x 512 threads (8 waves), 1 block/CU. Blocks 0..127: layer0 (8 ch each),
// 128..255: layer1. Weights = MFMA B-frags in registers (preloaded once).
// gates(16x32) = X(16xK) @ Wblk(32xK)^T via mfma_f32_16x16x32_bf16; batch padded 4->16
// (padding rows of X_lds left uninitialized: their D rows are never read).
// Sync: pure dataflow. cnt0[p] counts layer0 blocks done writing h0[p]; cnt1[p] ditto h1.
// Layer0 never waits on layer1 -> deadlock-free under any residency/dispatch order.
__global__ __launch_bounds__(512, 2) void k_lstm_fused(
    const float* __restrict__ X0,            // (B,U,4096)  eys@Wih0^T + bih0 + bhh0
    float* __restrict__ h0h,                 // (65,B,1024)
    float* __restrict__ h1h,                 // (65,B,1024)
    float* __restrict__ hdec,                // (B,U,1024) f32
    const unsigned short* __restrict__ W_hh0,
    const unsigned short* __restrict__ W_ih1,
    const unsigned short* __restrict__ W_hh1,
    const float* __restrict__ b_ih1,
    const float* __restrict__ b_hh1,
    int* __restrict__ cnt) {
  __shared__ unsigned short X_lds[16][2056];   // 16 x (2048 + 8 pad) bf16 = 65.8 KB
  __shared__ float red[8][2][16][4];           // wave partials, 4 KB
  __shared__ float gsum[32][4];
  int tid = threadIdx.x;
  int lane = tid & 63, w = tid >> 6;
  bool is1 = blockIdx.x >= 128;
  int base = (blockIdx.x & 127) * 8;
  int* cnt0 = cnt;
  int* cnt1 = cnt + 65 * 32;

  // ---- preload weight B-frags into registers (held across all steps) ----
  // B-frag (N x K tile, N=16): lane holds W[n0 + (lane&15)][k0 + (lane>>4)*8 + j]
  // block rows: nt*16+c -> gate (nt*2 + (c>>3)), channel base+(c&7)
  bf16x8 wf[2][8];
  int c = lane & 15;
  int grow0 = ((c >> 3)) * 1024 + base + (c & 7);        // nt=0: gates 0,1
  int grow1 = (2 + (c >> 3)) * 1024 + base + (c & 7);    // nt=1: gates 2,3
  int ksegs = is1 ? 8 : 4;
  int kb = w * (is1 ? 256 : 128);
#pragma unroll
  for (int nt = 0; nt < 2; nt++) {
    int grow = nt ? grow1 : grow0;
    for (int ks = 0; ks < ksegs; ks++) {
      int k = kb + ks * 32 + ((lane >> 4) << 3);
      const unsigned short* src;
      if (!is1)            src = W_hh0 + (size_t)grow * 1024 + k;
      else if (k < 1024)   src = W_ih1 + (size_t)grow * 1024 + k;
      else                 src = W_hh1 + (size_t)grow * 1024 + (k - 1024);
      wf[nt][ks] = *(const bf16x8*)src;
    }
  }

  // per-thread persistent cell state + layer1 bias sums (tid<32: ch=base+(tid>>2), b=tid&3)
  float creg = 0.f;
  float bsum0 = 0.f, bsum1 = 0.f, bsum2 = 0.f, bsum3 = 0.f;
  if (is1 && tid < 32) {
    int ch = base + (tid >> 2);
    bsum0 = b_ih1[ch] + b_hh1[ch];
    bsum1 = b_ih1[1024 + ch] + b_hh1[1024 + ch];
    bsum2 = b_ih1[2048 + ch] + b_hh1[2048 + ch];
    bsum3 = b_ih1[3072 + ch] + b_hh1[3072 + ch];
  }

  int pbeg = is1 ? 1 : 0, pend = is1 ? 64 : 63;
  for (int p = pbeg; p <= pend; p++) {
    // ---- dataflow wait ----
    if (tid == 0) {
      if (!is1) {
        if (p >= 1)
          while (__hip_atomic_load(&cnt0[p * 32], __ATOMIC_RELAXED, __HIP_MEMORY_SCOPE_AGENT) < 128)
            __builtin_amdgcn_s_sleep(1);
      } else {
        while (__hip_atomic_load(&cnt0[p * 32], __ATOMIC_RELAXED, __HIP_MEMORY_SCOPE_AGENT) < 128)
          __builtin_amdgcn_s_sleep(1);
        if (p >= 2)
          while (__hip_atomic_load(&cnt1[(p - 1) * 32], __ATOMIC_RELAXED, __HIP_MEMORY_SCOPE_AGENT) < 128)
            __builtin_amdgcn_s_sleep(1);
      }
    }
    __syncthreads();

    // ---- stage X into LDS (sc1 loads -> bf16) ----
    if (!is1) {
      int idx0 = tid * 8;                   // 8 f32 per thread, 4096 total
      const unsigned long long* src = (const unsigned long long*)(h0h + (size_t)p * 4096) + tid * 4;
      unsigned long long v[4];
#pragma unroll
      for (int i = 0; i < 4; i++)
        v[i] = __hip_atomic_load(src + i, __ATOMIC_RELAXED, __HIP_MEMORY_SCOPE_AGENT);
      bf16x8 r;
#pragma unroll
      for (int i = 0; i < 4; i++) {
        union { unsigned long long u; float f[2]; } cv; cv.u = v[i];
        r[2 * i] = (short)f2bf(cv.f[0]); r[2 * i + 1] = (short)f2bf(cv.f[1]);
      }
      *(bf16x8*)&X_lds[idx0 >> 10][idx0 & 1023] = r;
    } else {
      int idx0 = tid * 16;                  // 16 f32 per thread, 8192 total
      const float* fsrc; int b, k;
      if (idx0 < 4096) { fsrc = h0h + (size_t)p * 4096 + idx0; b = idx0 >> 10; k = idx0 & 1023; }
      else { int j = idx0 - 4096; fsrc = h1h + (size_t)(p - 1) * 4096 + j; b = j >> 10; k = 1024 + (j & 1023); }
      const unsigned long long* src = (const unsigned long long*)fsrc;
      unsigned long long v[8];
#pragma unroll
      for (int i = 0; i < 8; i++)
        v[i] = __hip_atomic_load(src + i, __ATOMIC_RELAXED, __HIP_MEMORY_SCOPE_AGENT);
      bf16x8 r0, r1;
#pragma unroll
      for (int i = 0; i < 4; i++) {
        union { unsigned long long u; float f[2]; } cv; cv.u = v[i];
        r0[2 * i] = (short)f2bf(cv.f[0]); r0[2 * i + 1] = (short)f2bf(cv.f[1]);
      }
#pragma unroll
      for (int i = 0; i < 4; i++) {
        union { unsigned long long u; float f[2]; } cv; cv.u = v[4 + i];
        r1[2 * i] = (short)f2bf(cv.f[0]); r1[2 * i + 1] = (short)f2bf(cv.f[1]);
      }
      *(bf16x8*)&X_lds[b][k] = r0;
      *(bf16x8*)&X_lds[b][k + 8] = r1;
    }
    __syncthreads();

    // ---- MFMA: gates partial for this wave's K-range ----
    f32x4 acc0 = {0.f, 0.f, 0.f, 0.f}, acc1 = {0.f, 0.f, 0.f, 0.f};
    if (!is1) {
#pragma unroll
      for (int ks = 0; ks < 4; ks++) {
        bf16x8 a = *(const bf16x8*)&X_lds[lane & 15][kb + ks * 32 + ((lane >> 4) << 3)];
        acc0 = __builtin_amdgcn_mfma_f32_16x16x32_bf16(a, wf[0][ks], acc0, 0, 0, 0);
        acc1 = __builtin_amdgcn_mfma_f32_16x16x32_bf16(a, wf[1][ks], acc1, 0, 0, 0);
      }
    } else {
#pragma unroll
      for (int ks = 0; ks < 8; ks++) {
        bf16x8 a = *(const bf16x8*)&X_lds[lane & 15][kb + ks * 32 + ((lane >> 4) << 3)];
        acc0 = __builtin_amdgcn_mfma_f32_16x16x32_bf16(a, wf[0][ks], acc0, 0, 0, 0);
        acc1 = __builtin_amdgcn_mfma_f32_16x16x32_bf16(a, wf[1][ks], acc1, 0, 0, 0);
      }
    }
    if (lane < 16) {          // D rows 0..3 (batch) live in lanes 0..15, reg q = batch
      *(f32x4*)&red[w][0][lane][0] = acc0;
      *(f32x4*)&red[w][1][lane][0] = acc1;
    }
    __syncthreads();
    if (tid < 128) {          // sum 8 wave partials -> gsum[gaterow][batch]
      int nt = tid >> 6, cc = (tid >> 2) & 15, q = tid & 3;
      float s = 0.f;
#pragma unroll
      for (int w8 = 0; w8 < 8; w8++) s += red[w8][nt][cc][q];
      gsum[nt * 16 + cc][q] = s;
    }
    __syncthreads();
    if (tid < 32) {
      int cl2 = tid >> 2, b = tid & 3;
      int ch = base + cl2;
      float gi = gsum[cl2][b], gf = gsum[8 + cl2][b];
      float gg = gsum[16 + cl2][b], go = gsum[24 + cl2][b];
      if (!is1) {
        const float* x0p = X0 + ((size_t)(b * 64 + p)) * 4096;
        gi += x0p[ch]; gf += x0p[1024 + ch]; gg += x0p[2048 + ch]; go += x0p[3072 + ch];
      } else {
        gi += bsum0; gf += bsum1; gg += bsum2; go += bsum3;
      }
      float ii = 1.f / (1.f + __expf(-gi));
      float ff = 1.f / (1.f + __expf(-gf));
      float oo = 1.f / (1.f + __expf(-go));
      float cn = ff * creg + ii * tanhf(gg);
      creg = cn;
      float hn = oo * tanhf(cn);
      if (!is1) {
        __hip_atomic_store(&h0h[(size_t)(p + 1) * 4096 + b * 1024 + ch], hn,
                           __ATOMIC_RELAXED, __HIP_MEMORY_SCOPE_AGENT);
      } else {
        __hip_atomic_store(&h1h[(size_t)p * 4096 + b * 1024 + ch], hn,
                           __ATOMIC_RELAXED, __HIP_MEMORY_SCOPE_AGENT);
        hdec[((size_t)(b * 64 + (p - 1))) * 1024 + ch] = hn;  // consumed after kernel end
      }
    }
    // ---- arrival ----
    asm volatile("s_waitcnt vmcnt(0)" ::: "memory");   // h stores at coherence point
    __syncthreads();
    if (tid == 0) {
      if (!is1)
        __hip_atomic_fetch_add(&cnt0[(p + 1) * 32], 1, __ATOMIC_RELAXED, __HIP_MEMORY_SCOPE_AGENT);
      else
        __hip_atomic_fetch_add(&cnt1[p * 32], 1, __ATOMIC_RELAXED, __HIP_MEMORY_SCOPE_AGENT);
    }
  }
}

// ---------------- joint: out[b,t,u,:] = tanh(encp[b,t,:]+decp[b,u,:]) @ Wout^T + bout ----
// 256 blocks x 512 threads; z-panel in regs; NONTEMPORAL f32 output stores.
__global__ __launch_bounds__(512) void k_joint(const float* __restrict__ encp,   // (B,T,512)
                                               const float* __restrict__ decp,   // (B,U,512)
                                               const unsigned short* __restrict__ Wout, // (2048,512) bf16
                                               const float* __restrict__ bout,   // (2048) f32
                                               float* __restrict__ out) {        // (B,T,U,2048) f32
  __shared__ unsigned short Wls[2][8192];   // 2 x 16KB: 128 n-rows x 64 k (swizzled)
  int tid = threadIdx.x;
  int lane = tid & 63, wid = tid >> 6;      // 8 waves
  int bidx = blockIdx.x;
  int b = bidx >> 6, tloc = bidx & 63;
  int t0 = tloc * 2;
  int wm = (wid >> 1) * 32;                 // 4 m-waves x 32 rows
  int wn = (wid & 1) * 64;                  // 2 n-waves x 64 cols

  // ---- prologue: issue stage of chunk 0 (overlaps with A-build) ----
  {
#pragma unroll
    for (int q = 0; q < 2; q++) {
      int idx = tid + q * 512;
      int n = idx >> 3, sl = idx & 7;
      int ss = sl ^ (n & 7);
      gload_lds16(Wout + (size_t)n * 512 + ss * 8, &Wls[0][idx * 8]);
    }
  }

  // ---- build A panel in registers: 2 m-frags x 16 k-frags, bf16x8 each ----
  bf16x8 afr[32];
#pragma unroll
  for (int mf = 0; mf < 2; mf++) {
    int rr = wm + mf * 16 + (lane & 15);
    int t = t0 + (rr >> 6), u = rr & 63;
    const float* ep = encp + ((size_t)(b * 128 + t)) * 512;
    const float* dp = decp + ((size_t)(b * 64 + u)) * 512;
#pragma unroll
    for (int kf = 0; kf < 16; kf++) {
      int k0 = kf * 32 + ((lane >> 4) << 3);
      bf16x8 v;
#pragma unroll
      for (int j = 0; j < 8; j++) {
        float x = ep[k0 + j] + dp[k0 + j];
        float e = __expf(x + x);
        v[j] = (short)f2bf(1.f - 2.f / (e + 1.f));
      }
      afr[mf * 16 + kf] = v;
    }
  }

  f32x4 acc[2][4];
#pragma unroll
  for (int mf = 0; mf < 2; mf++)
#pragma unroll
    for (int nf = 0; nf < 4; nf++) acc[mf][nf] = (f32x4){0.f, 0.f, 0.f, 0.f};

  // ---- main loop: 16 n-tiles x 8 k-chunks, depth-1 prefetch ----
  for (int c = 0; c < 128; c++) {
    int nt = c >> 3, kc = c & 7;
    __syncthreads();                    // drains vmcnt(0): chunk c is in LDS
    if (c < 127) {
      int c1i = c + 1;
      int nn0 = (c1i >> 3) << 7;
      int kb = (c1i & 7) * 64;
      unsigned short* dst = Wls[c1i & 1];
#pragma unroll
      for (int q = 0; q < 2; q++) {
        int idx = tid + q * 512;
        int n = idx >> 3, sl = idx & 7;
        int ss = sl ^ (n & 7);
        gload_lds16(Wout + (size_t)(nn0 + n) * 512 + kb + ss * 8, dst + idx * 8);
      }
    }
    const unsigned short* Wb = Wls[c & 1];
#pragma unroll
    for (int ks = 0; ks < 2; ks++) {
      bf16x8 bfr[4];
#pragma unroll
      for (int nf = 0; nf < 4; nf++) {
        int n = wn + nf * 16 + (lane & 15);
        int slot = ks * 4 + (lane >> 4);
        int phys = slot ^ (n & 7);
        bfr[nf] = *(const bf16x8*)(Wb + n * 64 + phys * 8);
      }
      int kf = kc * 2 + ks;
#pragma unroll
      for (int mf = 0; mf < 2; mf++)
#pragma unroll
        for (int nf = 0; nf < 4; nf++)
          acc[mf][nf] = __builtin_amdgcn_mfma_f32_16x16x32_bf16(afr[mf * 16 + kf], bfr[nf],
                                                                acc[mf][nf], 0, 0, 0);
    }
    if (kc == 7) {                      // epilogue for this n-tile
      int n0 = nt << 7;
#pragma unroll
      for (int mf = 0; mf < 2; mf++) {
        int rb = wm + mf * 16 + ((lane >> 4) << 2);
#pragma unroll
        for (int nf = 0; nf < 4; nf++) {
          int o = n0 + wn + nf * 16 + (lane & 15);
          float bb = bout[o];
#pragma unroll
          for (int q = 0; q < 4; q++) {
            int rr = rb + q;
            int t = t0 + (rr >> 6), u = rr & 63;
            __builtin_nontemporal_store(acc[mf][nf][q] + bb,
                &out[(((size_t)(b * 128 + t)) * 64 + u) * 2048 + o]);
          }
          acc[mf][nf] = (f32x4){0.f, 0.f, 0.f, 0.f};
        }
      }
    }
  }
}

// ---------------- launch ----------------
extern "C" void kernel_launch(void* const* d_in, const int* in_sizes, int n_in,
                              void* d_out, int out_size, void* d_ws, size_t ws_size,
                              hipStream_t stream) {
  const float* hs   = (const float*)d_in[0];
  const int*   ys   = (const int*)d_in[1];
  const float* emb  = (const float*)d_in[2];
  const float* Wih0 = (const float*)d_in[3];
  const float* Whh0 = (const float*)d_in[4];
  const float* bih0 = (const float*)d_in[5];
  const float* bhh0 = (const float*)d_in[6];
  const float* Wih1 = (const float*)d_in[7];
  const float* Whh1 = (const float*)d_in[8];
  const float* bih1 = (const float*)d_in[9];
  const float* bhh1 = (const float*)d_in[10];
  const float* Wenc = (const float*)d_in[11];
  const float* benc = (const float*)d_in[12];
  const float* Wdec = (const float*)d_in[13];
  const float* Wout = (const float*)d_in[14];
  const float* bout = (const float*)d_in[15];

  char* ws = (char*)d_ws;
  float*          eys   = (float*)(ws + 0);            // 256x512 f32        = 524,288
  float*          X0    = (float*)(ws + 524288);       // 256x4096 f32       = 4,194,304
  float*          encp  = (float*)(ws + 4718592);      // 512x512 f32        = 1,048,576
  float*          decp  = (float*)(ws + 5767168);      // 256x512 f32        = 524,288
  float*          h0h   = (float*)(ws + 6291456);      // 65x4096 f32        = 1,064,960
  float*          h1h   = (float*)(ws + 7356416);      // 65x4096 f32        = 1,064,960
  float*          hdec  = (float*)(ws + 8421376);      // 256x1024 f32       = 1,048,576
  int*            cnt   = (int*)(ws + 9469952);        // 2x65 step counters  = 16,640
  unsigned short* Whh0b = (unsigned short*)(ws + 9502720);   // 4M bf16      = 8,388,608
  unsigned short* Wih1b = (unsigned short*)(ws + 17891328);  // 4M bf16      = 8,388,608
  unsigned short* Whh1b = (unsigned short*)(ws + 26279936);  // 4M bf16      = 8,388,608
  unsigned short* Woutb = (unsigned short*)(ws + 34668544);  // 1M bf16      = 2,097,152
  float*          out   = (float*)d_out;                     // total ws = 36,765,696 B

  // weight conversion (bf16 for LSTM recurrent mats + Wout for global_load_lds)
  k_cvt<<<6656, 256, 0, stream>>>(Whh0, Wih1, Whh1, Wout, Whh0b, Wih1b, Whh1b, Woutb);
  k_prep<<<64, 256, 0, stream>>>(ys, emb, eys, h0h, h1h, cnt);
  // X0 = eys @ Wih0^T + bih0 + bhh0   (M=256, N=4096, K=512)
  k_gemm_bias<<<256, 256, 0, stream>>>(eys, Wih0, bih0, bhh0, X0, 256, 4096, 512);
  // encp = hs @ Wenc^T + benc         (M=512, N=512, K=512)
  k_gemm_bias<<<64, 256, 0, stream>>>(hs, Wenc, benc, nullptr, encp, 512, 512, 512);
  // fused LSTM: MFMA + per-step dataflow counters
  k_lstm_fused<<<256, 512, 0, stream>>>(X0, h0h, h1h, hdec,
                                        Whh0b, Wih1b, Whh1b, bih1, bhh1, cnt);
  // decp = hdec @ Wdec^T              (M=256, N=512, K=1024)
  k_gemm_bias<<<32, 256, 0, stream>>>(hdec, Wdec, nullptr, nullptr, decp, 256, 512, 1024);
  // joint
  k_joint<<<256, 512, 0, stream>>>(encp, decp, Woutb, bout, out);
}

// Round 7
// 874.315 us; speedup vs baseline: 5.4286x; 1.0844x over previous
//
#include <hip/hip_runtime.h>
#include <stdint.h>

typedef short bf16x8 __attribute__((ext_vector_type(8)));
typedef float f32x4 __attribute__((ext_vector_type(4)));

__device__ __forceinline__ unsigned short f2bf(float f) {
  union { float f; unsigned int i; } v; v.f = f;
  unsigned int r = v.i + 0x7FFF + ((v.i >> 16) & 1);
  return (unsigned short)(r >> 16);
}
__device__ __forceinline__ void gload_lds16(const void* g, void* l) {
  __builtin_amdgcn_global_load_lds(
      (const __attribute__((address_space(1))) unsigned int*)g,
      (__attribute__((address_space(3))) unsigned int*)l,
      16, 0, 0);
}

// ---------------- convert f32 weights -> bf16 (Whh0, Wih1, Whh1, Wout) ----------------
__global__ __launch_bounds__(256) void k_cvt(const float* __restrict__ s0, const float* __restrict__ s1,
                                             const float* __restrict__ s2, const float* __restrict__ s3,
                                             unsigned short* __restrict__ d0, unsigned short* __restrict__ d1,
                                             unsigned short* __restrict__ d2, unsigned short* __restrict__ d3) {
  int j = blockIdx.x * 256 + threadIdx.x;   // 6656*256 = 1,703,936 vec8 jobs exactly
  const float* s; unsigned short* d; int o;
  if (j < 524288)       { s = s0; d = d0; o = j; }
  else if (j < 1048576) { s = s1; d = d1; o = j - 524288; }
  else if (j < 1572864) { s = s2; d = d2; o = j - 1048576; }
  else                  { s = s3; d = d3; o = j - 1572864; }
  size_t off = (size_t)o * 8;
  f32x4 v0 = *(const f32x4*)(s + off);
  f32x4 v1 = *(const f32x4*)(s + off + 4);
  bf16x8 r;
#pragma unroll
  for (int k = 0; k < 4; k++) { r[k] = (short)f2bf(v0[k]); r[4 + k] = (short)f2bf(v1[k]); }
  *(bf16x8*)(d + off) = r;
}

// ---------------- prep: embedding gather (f32) + zero state + zero flags ----------------
__global__ __launch_bounds__(256) void k_prep(const int* __restrict__ ys,
                                              const float* __restrict__ embed,
                                              float* __restrict__ eys,
                                              float* __restrict__ h0h, float* __restrict__ h1h,
                                              int* __restrict__ flags) {
  int idx = blockIdx.x * 256 + threadIdx.x;   // 16384 threads
  int row = idx >> 6;
  int e = (idx & 63) * 8;
  int y = ys[row];
  f32x4 v0 = {0.f, 0.f, 0.f, 0.f}, v1 = {0.f, 0.f, 0.f, 0.f};
  if (y != 0) {
    v0 = *(const f32x4*)(embed + (size_t)y * 512 + e);
    v1 = *(const f32x4*)(embed + (size_t)y * 512 + e + 4);
  }
  *(f32x4*)(eys + (size_t)row * 512 + e) = v0;
  *(f32x4*)(eys + (size_t)row * 512 + e + 4) = v1;
  if (idx < 4096) { h0h[idx] = 0.f; h1h[idx] = 0.f; }
  if (idx < 256) flags[idx] = 0;   // flags0[128] + flags1[128]
}

// -------- generic small GEMM: C(f32 MxN) = A(f32 MxK) @ W(f32 NxK)^T + b1 + b2 --------
__global__ __launch_bounds__(256) void k_gemm_bias(const float* __restrict__ A,
                                                   const float* __restrict__ W,
                                                   const float* __restrict__ b1,
                                                   const float* __restrict__ b2,
                                                   float* __restrict__ C,
                                                   int M, int N, int K) {
  __shared__ unsigned short Als[64][40];
  __shared__ unsigned short Wls[64][40];
  int tid = threadIdx.x;
  int lane = tid & 63, wid = tid >> 6;
  int mtiles = M >> 6;
  int mt = blockIdx.x % mtiles, nt = blockIdx.x / mtiles;
  int srow = tid >> 2, sseg = tid & 3;
  f32x4 acc[4];
#pragma unroll
  for (int nf = 0; nf < 4; nf++) acc[nf] = (f32x4){0.f, 0.f, 0.f, 0.f};

  for (int kc = 0; kc < K; kc += 32) {
    const float* ap = A + (size_t)(mt * 64 + srow) * K + kc + sseg * 8;
    const float* wp = W + (size_t)(nt * 64 + srow) * K + kc + sseg * 8;
    f32x4 a0 = *(const f32x4*)ap, a1 = *(const f32x4*)(ap + 4);
    f32x4 w0 = *(const f32x4*)wp, w1 = *(const f32x4*)(wp + 4);
    bf16x8 av, wv;
#pragma unroll
    for (int k = 0; k < 4; k++) {
      av[k] = (short)f2bf(a0[k]); av[4 + k] = (short)f2bf(a1[k]);
      wv[k] = (short)f2bf(w0[k]); wv[4 + k] = (short)f2bf(w1[k]);
    }
    __syncthreads();
    *(bf16x8*)(&Als[srow][sseg * 8]) = av;
    *(bf16x8*)(&Wls[srow][sseg * 8]) = wv;
    __syncthreads();
    bf16x8 af = *(const bf16x8*)(&Als[wid * 16 + (lane & 15)][(lane >> 4) * 8]);
#pragma unroll
    for (int nf = 0; nf < 4; nf++) {
      bf16x8 bf = *(const bf16x8*)(&Wls[nf * 16 + (lane & 15)][(lane >> 4) * 8]);
      acc[nf] = __builtin_amdgcn_mfma_f32_16x16x32_bf16(af, bf, acc[nf], 0, 0, 0);
    }
  }
  int rloc = (lane >> 4) * 4;
  int col0 = lane & 15;
#pragma unroll
  for (int nf = 0; nf < 4; nf++) {
    int n = nt * 64 + nf * 16 + col0;
    float bias = 0.f;
    if (b1) bias += b1[n];
    if (b2) bias += b2[n];
#pragma unroll
    for (int r = 0; r < 4; r++) {
      int m = mt * 64 + wid * 16 + rloc + r;
      C[(size_t)m * N + n] = acc[nf][r] + bias;
    }
  }
}

// ---------------- fused LSTM: MFMA GEMV + store-only flags (no atomic RMW) ----------
// 256 blocks x 512 threads. Blocks 0..127: layer0 (8 ch each), 128..255: layer1.
// Weights = MFMA B-frags in registers. Sync: flags0[b] = highest h0 step written by
// layer0 block b (plain sc1 store); consumers poll all 128 flags wave-parallel.
// Layer0 never waits on layer1 -> deadlock-free under any residency/dispatch order.
__global__ __launch_bounds__(512, 2) void k_lstm_fused(
    const float* __restrict__ X0,            // (B,U,4096)  eys@Wih0^T + bih0 + bhh0
    float* __restrict__ h0h,                 // (65,B,1024)
    float* __restrict__ h1h,                 // (65,B,1024)
    float* __restrict__ hdec,                // (B,U,1024) f32
    const unsigned short* __restrict__ W_hh0,
    const unsigned short* __restrict__ W_ih1,
    const unsigned short* __restrict__ W_hh1,
    const float* __restrict__ b_ih1,
    const float* __restrict__ b_hh1,
    int* __restrict__ flags) {               // [0..127]=layer0, [128..255]=layer1
  __shared__ unsigned short X_lds[16][2072];   // stride 2072 bf16 = 1036 dw = 12 mod 32
  __shared__ float red[8][2][16][4];
  __shared__ float gsum[32][4];
  int tid = threadIdx.x;
  int lane = tid & 63, w = tid >> 6;
  bool is1 = blockIdx.x >= 128;
  int bid7 = blockIdx.x & 127;
  int base = bid7 * 8;

  // ---- preload weight B-frags into registers (held across all steps) ----
  bf16x8 wf[2][8];
  int c = lane & 15;
  int grow0 = ((c >> 3)) * 1024 + base + (c & 7);        // nt=0: gates 0,1
  int grow1 = (2 + (c >> 3)) * 1024 + base + (c & 7);    // nt=1: gates 2,3
  int ksegs = is1 ? 8 : 4;
  int kb = w * (is1 ? 256 : 128);
#pragma unroll
  for (int nt = 0; nt < 2; nt++) {
    int grow = nt ? grow1 : grow0;
    for (int ks = 0; ks < ksegs; ks++) {
      int k = kb + ks * 32 + ((lane >> 4) << 3);
      const unsigned short* src;
      if (!is1)            src = W_hh0 + (size_t)grow * 1024 + k;
      else if (k < 1024)   src = W_ih1 + (size_t)grow * 1024 + k;
      else                 src = W_hh1 + (size_t)grow * 1024 + (k - 1024);
      wf[nt][ks] = *(const bf16x8*)src;
    }
  }

  // per-thread persistent cell state + layer1 bias sums (tid<32: ch=base+(tid>>2), b=tid&3)
  float creg = 0.f;
  float bsum0 = 0.f, bsum1 = 0.f, bsum2 = 0.f, bsum3 = 0.f;
  if (is1 && tid < 32) {
    int ch = base + (tid >> 2);
    bsum0 = b_ih1[ch] + b_hh1[ch];
    bsum1 = b_ih1[1024 + ch] + b_hh1[1024 + ch];
    bsum2 = b_ih1[2048 + ch] + b_hh1[2048 + ch];
    bsum3 = b_ih1[3072 + ch] + b_hh1[3072 + ch];
  }

  int pbeg = is1 ? 1 : 0, pend = is1 ? 64 : 63;
  for (int p = pbeg; p <= pend; p++) {
    // ---- dataflow wait: h0h[p] ready (and h1h[p-1] for layer1), wave 0 polls ----
    if (w == 0 && p > 0) {
      while (true) {
        int a0 = __hip_atomic_load(&flags[lane], __ATOMIC_RELAXED, __HIP_MEMORY_SCOPE_AGENT);
        int a1 = __hip_atomic_load(&flags[64 + lane], __ATOMIC_RELAXED, __HIP_MEMORY_SCOPE_AGENT);
        bool ok = (a0 >= p) && (a1 >= p);
        if (is1 && p >= 2) {
          int b0 = __hip_atomic_load(&flags[128 + lane], __ATOMIC_RELAXED, __HIP_MEMORY_SCOPE_AGENT);
          int b1v = __hip_atomic_load(&flags[192 + lane], __ATOMIC_RELAXED, __HIP_MEMORY_SCOPE_AGENT);
          ok = ok && (b0 >= p - 1) && (b1v >= p - 1);
        }
        if (__all(ok)) break;
        __builtin_amdgcn_s_sleep(8);
      }
    }
    __syncthreads();

    // ---- stage X into LDS (sc1 loads -> bf16) ----
    if (!is1) {
      int idx0 = tid * 8;                   // 8 f32 per thread, 4096 total
      const unsigned long long* src = (const unsigned long long*)(h0h + (size_t)p * 4096) + tid * 4;
      unsigned long long v[4];
#pragma unroll
      for (int i = 0; i < 4; i++)
        v[i] = __hip_atomic_load(src + i, __ATOMIC_RELAXED, __HIP_MEMORY_SCOPE_AGENT);
      bf16x8 r;
#pragma unroll
      for (int i = 0; i < 4; i++) {
        union { unsigned long long u; float f[2]; } cv; cv.u = v[i];
        r[2 * i] = (short)f2bf(cv.f[0]); r[2 * i + 1] = (short)f2bf(cv.f[1]);
      }
      *(bf16x8*)&X_lds[idx0 >> 10][idx0 & 1023] = r;
    } else {
      int idx0 = tid * 16;                  // 16 f32 per thread, 8192 total
      const float* fsrc; int b, k;
      if (idx0 < 4096) { fsrc = h0h + (size_t)p * 4096 + idx0; b = idx0 >> 10; k = idx0 & 1023; }
      else { int j = idx0 - 4096; fsrc = h1h + (size_t)(p - 1) * 4096 + j; b = j >> 10; k = 1024 + (j & 1023); }
      const unsigned long long* src = (const unsigned long long*)fsrc;
      unsigned long long v[8];
#pragma unroll
      for (int i = 0; i < 8; i++)
        v[i] = __hip_atomic_load(src + i, __ATOMIC_RELAXED, __HIP_MEMORY_SCOPE_AGENT);
      bf16x8 r0, r1;
#pragma unroll
      for (int i = 0; i < 4; i++) {
        union { unsigned long long u; float f[2]; } cv; cv.u = v[i];
        r0[2 * i] = (short)f2bf(cv.f[0]); r0[2 * i + 1] = (short)f2bf(cv.f[1]);
      }
#pragma unroll
      for (int i = 0; i < 4; i++) {
        union { unsigned long long u; float f[2]; } cv; cv.u = v[4 + i];
        r1[2 * i] = (short)f2bf(cv.f[0]); r1[2 * i + 1] = (short)f2bf(cv.f[1]);
      }
      *(bf16x8*)&X_lds[b][k] = r0;
      *(bf16x8*)&X_lds[b][k + 8] = r1;
    }
    __syncthreads();

    // ---- MFMA: gates partial for this wave's K-range ----
    f32x4 acc0 = {0.f, 0.f, 0.f, 0.f}, acc1 = {0.f, 0.f, 0.f, 0.f};
    if (!is1) {
#pragma unroll
      for (int ks = 0; ks < 4; ks++) {
        bf16x8 a = *(const bf16x8*)&X_lds[lane & 15][kb + ks * 32 + ((lane >> 4) << 3)];
        acc0 = __builtin_amdgcn_mfma_f32_16x16x32_bf16(a, wf[0][ks], acc0, 0, 0, 0);
        acc1 = __builtin_amdgcn_mfma_f32_16x16x32_bf16(a, wf[1][ks], acc1, 0, 0, 0);
      }
    } else {
#pragma unroll
      for (int ks = 0; ks < 8; ks++) {
        bf16x8 a = *(const bf16x8*)&X_lds[lane & 15][kb + ks * 32 + ((lane >> 4) << 3)];
        acc0 = __builtin_amdgcn_mfma_f32_16x16x32_bf16(a, wf[0][ks], acc0, 0, 0, 0);
        acc1 = __builtin_amdgcn_mfma_f32_16x16x32_bf16(a, wf[1][ks], acc1, 0, 0, 0);
      }
    }
    if (lane < 16) {          // D rows 0..3 (batch) live in lanes 0..15, reg q = batch
      *(f32x4*)&red[w][0][lane][0] = acc0;
      *(f32x4*)&red[w][1][lane][0] = acc1;
    }
    __syncthreads();
    if (tid < 128) {          // sum 8 wave partials -> gsum[gaterow][batch]
      int nt = tid >> 6, cc = (tid >> 2) & 15, q = tid & 3;
      float s = 0.f;
#pragma unroll
      for (int w8 = 0; w8 < 8; w8++) s += red[w8][nt][cc][q];
      gsum[nt * 16 + cc][q] = s;
    }
    __syncthreads();
    if (tid < 32) {
      int cl2 = tid >> 2, b = tid & 3;
      int ch = base + cl2;
      float gi = gsum[cl2][b], gf = gsum[8 + cl2][b];
      float gg = gsum[16 + cl2][b], go = gsum[24 + cl2][b];
      if (!is1) {
        const float* x0p = X0 + ((size_t)(b * 64 + p)) * 4096;
        gi += x0p[ch]; gf += x0p[1024 + ch]; gg += x0p[2048 + ch]; go += x0p[3072 + ch];
      } else {
        gi += bsum0; gf += bsum1; gg += bsum2; go += bsum3;
      }
      float ii = 1.f / (1.f + __expf(-gi));
      float ff = 1.f / (1.f + __expf(-gf));
      float oo = 1.f / (1.f + __expf(-go));
      float cn = ff * creg + ii * tanhf(gg);
      creg = cn;
      float hn = oo * tanhf(cn);
      if (!is1) {
        __hip_atomic_store(&h0h[(size_t)(p + 1) * 4096 + b * 1024 + ch], hn,
                           __ATOMIC_RELAXED, __HIP_MEMORY_SCOPE_AGENT);
      } else {
        __hip_atomic_store(&h1h[(size_t)p * 4096 + b * 1024 + ch], hn,
                           __ATOMIC_RELAXED, __HIP_MEMORY_SCOPE_AGENT);
        hdec[((size_t)(b * 64 + (p - 1))) * 1024 + ch] = hn;  // consumed after kernel end
      }
    }
    // ---- arrival: wave 0's h-stores flushed, then one flag store (no RMW) ----
    asm volatile("s_waitcnt vmcnt(0)" ::: "memory");
    __syncthreads();
    if (tid == 0) {
      if (!is1)
        __hip_atomic_store(&flags[bid7], p + 1, __ATOMIC_RELAXED, __HIP_MEMORY_SCOPE_AGENT);
      else
        __hip_atomic_store(&flags[128 + bid7], p, __ATOMIC_RELAXED, __HIP_MEMORY_SCOPE_AGENT);
    }
  }
}

// ---------------- joint: out[b,t,u,:] = tanh(encp[b,t,:]+decp[b,u,:]) @ Wout^T + bout ----
// 256 blocks x 512 threads; z-panel in regs; NONTEMPORAL f32 output stores.
__global__ __launch_bounds__(512) void k_joint(const float* __restrict__ encp,   // (B,T,512)
                                               const float* __restrict__ decp,   // (B,U,512)
                                               const unsigned short* __restrict__ Wout, // (2048,512) bf16
                                               const float* __restrict__ bout,   // (2048) f32
                                               float* __restrict__ out) {        // (B,T,U,2048) f32
  __shared__ unsigned short Wls[2][8192];   // 2 x 16KB: 128 n-rows x 64 k (swizzled)
  int tid = threadIdx.x;
  int lane = tid & 63, wid = tid >> 6;      // 8 waves
  int bidx = blockIdx.x;
  int b = bidx >> 6, tloc = bidx & 63;
  int t0 = tloc * 2;
  int wm = (wid >> 1) * 32;                 // 4 m-waves x 32 rows
  int wn = (wid & 1) * 64;                  // 2 n-waves x 64 cols

  // ---- prologue: issue stage of chunk 0 (overlaps with A-build) ----
  {
#pragma unroll
    for (int q = 0; q < 2; q++) {
      int idx = tid + q * 512;
      int n = idx >> 3, sl = idx & 7;
      int ss = sl ^ (n & 7);
      gload_lds16(Wout + (size_t)n * 512 + ss * 8, &Wls[0][idx * 8]);
    }
  }

  // ---- build A panel in registers: 2 m-frags x 16 k-frags, bf16x8 each ----
  bf16x8 afr[32];
#pragma unroll
  for (int mf = 0; mf < 2; mf++) {
    int rr = wm + mf * 16 + (lane & 15);
    int t = t0 + (rr >> 6), u = rr & 63;
    const float* ep = encp + ((size_t)(b * 128 + t)) * 512;
    const float* dp = decp + ((size_t)(b * 64 + u)) * 512;
#pragma unroll
    for (int kf = 0; kf < 16; kf++) {
      int k0 = kf * 32 + ((lane >> 4) << 3);
      bf16x8 v;
#pragma unroll
      for (int j = 0; j < 8; j++) {
        float x = ep[k0 + j] + dp[k0 + j];
        float e = __expf(x + x);
        v[j] = (short)f2bf(1.f - 2.f / (e + 1.f));
      }
      afr[mf * 16 + kf] = v;
    }
  }

  f32x4 acc[2][4];
#pragma unroll
  for (int mf = 0; mf < 2; mf++)
#pragma unroll
    for (int nf = 0; nf < 4; nf++) acc[mf][nf] = (f32x4){0.f, 0.f, 0.f, 0.f};

  // ---- main loop: 16 n-tiles x 8 k-chunks, depth-1 prefetch ----
  for (int c = 0; c < 128; c++) {
    int nt = c >> 3, kc = c & 7;
    __syncthreads();                    // drains vmcnt(0): chunk c is in LDS
    if (c < 127) {
      int c1i = c + 1;
      int nn0 = (c1i >> 3) << 7;
      int kb = (c1i & 7) * 64;
      unsigned short* dst = Wls[c1i & 1];
#pragma unroll
      for (int q = 0; q < 2; q++) {
        int idx = tid + q * 512;
        int n = idx >> 3, sl = idx & 7;
        int ss = sl ^ (n & 7);
        gload_lds16(Wout + (size_t)(nn0 + n) * 512 + kb + ss * 8, dst + idx * 8);
      }
    }
    const unsigned short* Wb = Wls[c & 1];
#pragma unroll
    for (int ks = 0; ks < 2; ks++) {
      bf16x8 bfr[4];
#pragma unroll
      for (int nf = 0; nf < 4; nf++) {
        int n = wn + nf * 16 + (lane & 15);
        int slot = ks * 4 + (lane >> 4);
        int phys = slot ^ (n & 7);
        bfr[nf] = *(const bf16x8*)(Wb + n * 64 + phys * 8);
      }
      int kf = kc * 2 + ks;
#pragma unroll
      for (int mf = 0; mf < 2; mf++)
#pragma unroll
        for (int nf = 0; nf < 4; nf++)
          acc[mf][nf] = __builtin_amdgcn_mfma_f32_16x16x32_bf16(afr[mf * 16 + kf], bfr[nf],
                                                                acc[mf][nf], 0, 0, 0);
    }
    if (kc == 7) {                      // epilogue for this n-tile
      int n0 = nt << 7;
#pragma unroll
      for (int mf = 0; mf < 2; mf++) {
        int rb = wm + mf * 16 + ((lane >> 4) << 2);
#pragma unroll
        for (int nf = 0; nf < 4; nf++) {
          int o = n0 + wn + nf * 16 + (lane & 15);
          float bb = bout[o];
#pragma unroll
          for (int q = 0; q < 4; q++) {
            int rr = rb + q;
            int t = t0 + (rr >> 6), u = rr & 63;
            __builtin_nontemporal_store(acc[mf][nf][q] + bb,
                &out[(((size_t)(b * 128 + t)) * 64 + u) * 2048 + o]);
          }
          acc[mf][nf] = (f32x4){0.f, 0.f, 0.f, 0.f};
        }
      }
    }
  }
}

// ---------------- launch ----------------
extern "C" void kernel_launch(void* const* d_in, const int* in_sizes, int n_in,
                              void* d_out, int out_size, void* d_ws, size_t ws_size,
                              hipStream_t stream) {
  const float* hs   = (const float*)d_in[0];
  const int*   ys   = (const int*)d_in[1];
  const float* emb  = (const float*)d_in[2];
  const float* Wih0 = (const float*)d_in[3];
  const float* Whh0 = (const float*)d_in[4];
  const float* bih0 = (const float*)d_in[5];
  const float* bhh0 = (const float*)d_in[6];
  const float* Wih1 = (const float*)d_in[7];
  const float* Whh1 = (const float*)d_in[8];
  const float* bih1 = (const float*)d_in[9];
  const float* bhh1 = (const float*)d_in[10];
  const float* Wenc = (const float*)d_in[11];
  const float* benc = (const float*)d_in[12];
  const float* Wdec = (const float*)d_in[13];
  const float* Wout = (const float*)d_in[14];
  const float* bout = (const float*)d_in[15];

  char* ws = (char*)d_ws;
  float*          eys   = (float*)(ws + 0);            // 256x512 f32        = 524,288
  float*          X0    = (float*)(ws + 524288);       // 256x4096 f32       = 4,194,304
  float*          encp  = (float*)(ws + 4718592);      // 512x512 f32        = 1,048,576
  float*          decp  = (float*)(ws + 5767168);      // 256x512 f32        = 524,288
  float*          h0h   = (float*)(ws + 6291456);      // 65x4096 f32        = 1,064,960
  float*          h1h   = (float*)(ws + 7356416);      // 65x4096 f32        = 1,064,960
  float*          hdec  = (float*)(ws + 8421376);      // 256x1024 f32       = 1,048,576
  int*            flags = (int*)(ws + 9469952);        // 256 ints            = 1,024
  unsigned short* Whh0b = (unsigned short*)(ws + 9502720);   // 4M bf16      = 8,388,608
  unsigned short* Wih1b = (unsigned short*)(ws + 17891328);  // 4M bf16      = 8,388,608
  unsigned short* Whh1b = (unsigned short*)(ws + 26279936);  // 4M bf16      = 8,388,608
  unsigned short* Woutb = (unsigned short*)(ws + 34668544);  // 1M bf16      = 2,097,152
  float*          out   = (float*)d_out;                     // total ws = 36,765,696 B

  // weight conversion (bf16 for LSTM recurrent mats + Wout for global_load_lds)
  k_cvt<<<6656, 256, 0, stream>>>(Whh0, Wih1, Whh1, Wout, Whh0b, Wih1b, Whh1b, Woutb);
  k_prep<<<64, 256, 0, stream>>>(ys, emb, eys, h0h, h1h, flags);
  // X0 = eys @ Wih0^T + bih0 + bhh0   (M=256, N=4096, K=512)
  k_gemm_bias<<<256, 256, 0, stream>>>(eys, Wih0, bih0, bhh0, X0, 256, 4096, 512);
  // encp = hs @ Wenc^T + benc         (M=512, N=512, K=512)
  k_gemm_bias<<<64, 256, 0, stream>>>(hs, Wenc, benc, nullptr, encp, 512, 512, 512);
  // fused LSTM: MFMA + store-only flag dataflow
  k_lstm_fused<<<256, 512, 0, stream>>>(X0, h0h, h1h, hdec,
                                        Whh0b, Wih1b, Whh1b, bih1, bhh1, flags);
  // decp = hdec @ Wdec^T              (M=256, N=512, K=1024)
  k_gemm_bias<<<32, 256, 0, stream>>>(hdec, Wdec, nullptr, nullptr, decp, 256, 512, 1024);
  // joint
  k_joint<<<256, 512, 0, stream>>>(encp, decp, Woutb, bout, out);
}

// Round 8
// 739.518 us; speedup vs baseline: 6.4181x; 1.1823x over previous
//
#include <hip/hip_runtime.h>
#include <stdint.h>

typedef short bf16x8 __attribute__((ext_vector_type(8)));
typedef float f32x4 __attribute__((ext_vector_type(4)));

__device__ __forceinline__ unsigned short f2bf(float f) {
  union { float f; unsigned int i; } v; v.f = f;
  unsigned int r = v.i + 0x7FFF + ((v.i >> 16) & 1);
  return (unsigned short)(r >> 16);
}
__device__ __forceinline__ void gload_lds16(const void* g, void* l) {
  __builtin_amdgcn_global_load_lds(
      (const __attribute__((address_space(1))) unsigned int*)g,
      (__attribute__((address_space(3))) unsigned int*)l,
      16, 0, 0);
}

// ---------------- convert f32 weights -> bf16 (Whh0, Wih1, Whh1, Wout) ----------------
__global__ __launch_bounds__(256) void k_cvt(const float* __restrict__ s0, const float* __restrict__ s1,
                                             const float* __restrict__ s2, const float* __restrict__ s3,
                                             unsigned short* __restrict__ d0, unsigned short* __restrict__ d1,
                                             unsigned short* __restrict__ d2, unsigned short* __restrict__ d3) {
  int j = blockIdx.x * 256 + threadIdx.x;   // 6656*256 = 1,703,936 vec8 jobs exactly
  const float* s; unsigned short* d; int o;
  if (j < 524288)       { s = s0; d = d0; o = j; }
  else if (j < 1048576) { s = s1; d = d1; o = j - 524288; }
  else if (j < 1572864) { s = s2; d = d2; o = j - 1048576; }
  else                  { s = s3; d = d3; o = j - 1572864; }
  size_t off = (size_t)o * 8;
  f32x4 v0 = *(const f32x4*)(s + off);
  f32x4 v1 = *(const f32x4*)(s + off + 4);
  bf16x8 r;
#pragma unroll
  for (int k = 0; k < 4; k++) { r[k] = (short)f2bf(v0[k]); r[4 + k] = (short)f2bf(v1[k]); }
  *(bf16x8*)(d + off) = r;
}

// ---------------- prep: embedding gather (f32) + zero state + zero flags ----------------
__global__ __launch_bounds__(256) void k_prep(const int* __restrict__ ys,
                                              const float* __restrict__ embed,
                                              float* __restrict__ eys,
                                              float* __restrict__ h0h, float* __restrict__ h1h,
                                              int* __restrict__ flags) {
  int idx = blockIdx.x * 256 + threadIdx.x;   // 16384 threads
  int row = idx >> 6;
  int e = (idx & 63) * 8;
  int y = ys[row];
  f32x4 v0 = {0.f, 0.f, 0.f, 0.f}, v1 = {0.f, 0.f, 0.f, 0.f};
  if (y != 0) {
    v0 = *(const f32x4*)(embed + (size_t)y * 512 + e);
    v1 = *(const f32x4*)(embed + (size_t)y * 512 + e + 4);
  }
  *(f32x4*)(eys + (size_t)row * 512 + e) = v0;
  *(f32x4*)(eys + (size_t)row * 512 + e + 4) = v1;
  if (idx < 4096) { h0h[idx] = 0.f; h1h[idx] = 0.f; }
  if (idx < 64) flags[idx] = 0;
}

// -------- generic small GEMM: C(f32 MxN) = A(f32 MxK) @ W(f32 NxK)^T + b1 + b2 --------
__global__ __launch_bounds__(256) void k_gemm_bias(const float* __restrict__ A,
                                                   const float* __restrict__ W,
                                                   const float* __restrict__ b1,
                                                   const float* __restrict__ b2,
                                                   float* __restrict__ C,
                                                   int M, int N, int K) {
  __shared__ unsigned short Als[64][40];
  __shared__ unsigned short Wls[64][40];
  int tid = threadIdx.x;
  int lane = tid & 63, wid = tid >> 6;
  int mtiles = M >> 6;
  int mt = blockIdx.x % mtiles, nt = blockIdx.x / mtiles;
  int srow = tid >> 2, sseg = tid & 3;
  f32x4 acc[4];
#pragma unroll
  for (int nf = 0; nf < 4; nf++) acc[nf] = (f32x4){0.f, 0.f, 0.f, 0.f};

  for (int kc = 0; kc < K; kc += 32) {
    const float* ap = A + (size_t)(mt * 64 + srow) * K + kc + sseg * 8;
    const float* wp = W + (size_t)(nt * 64 + srow) * K + kc + sseg * 8;
    f32x4 a0 = *(const f32x4*)ap, a1 = *(const f32x4*)(ap + 4);
    f32x4 w0 = *(const f32x4*)wp, w1 = *(const f32x4*)(wp + 4);
    bf16x8 av, wv;
#pragma unroll
    for (int k = 0; k < 4; k++) {
      av[k] = (short)f2bf(a0[k]); av[4 + k] = (short)f2bf(a1[k]);
      wv[k] = (short)f2bf(w0[k]); wv[4 + k] = (short)f2bf(w1[k]);
    }
    __syncthreads();
    *(bf16x8*)(&Als[srow][sseg * 8]) = av;
    *(bf16x8*)(&Wls[srow][sseg * 8]) = wv;
    __syncthreads();
    bf16x8 af = *(const bf16x8*)(&Als[wid * 16 + (lane & 15)][(lane >> 4) * 8]);
#pragma unroll
    for (int nf = 0; nf < 4; nf++) {
      bf16x8 bf = *(const bf16x8*)(&Wls[nf * 16 + (lane & 15)][(lane >> 4) * 8]);
      acc[nf] = __builtin_amdgcn_mfma_f32_16x16x32_bf16(af, bf, acc[nf], 0, 0, 0);
    }
  }
  int rloc = (lane >> 4) * 4;
  int col0 = lane & 15;
#pragma unroll
  for (int nf = 0; nf < 4; nf++) {
    int n = nt * 64 + nf * 16 + col0;
    float bias = 0.f;
    if (b1) bias += b1[n];
    if (b2) bias += b2[n];
#pragma unroll
    for (int r = 0; r < 4; r++) {
      int m = mt * 64 + wid * 16 + rloc + r;
      C[(size_t)m * N + n] = acc[nf][r] + bias;
    }
  }
}

// ---------------- fused LSTM v3: 64 merged blocks, single sync domain ----------------
// 64 blocks x 512 threads (8 waves). Block b owns channels [b*16, b*16+16) of BOTH layers.
// Round p: layer0 step p (p<64) || layer1 step p-1 (p>=1). Both consume h0h[p]; layer1
// also consumes h1h[p-1]. One staged X tile serves both. One flag store + one 64-flag
// poll per round. Weight B-frags (layer0: 64 VGPR, layer1: 128 VGPR) register-resident.
__global__ __launch_bounds__(512, 2) void k_lstm_fused(
    const float* __restrict__ X0,            // (B,U,4096)  eys@Wih0^T + bih0 + bhh0
    float* __restrict__ h0h,                 // (65,B,1024)
    float* __restrict__ h1h,                 // (65,B,1024)
    float* __restrict__ hdec,                // (B,U,1024) f32
    const unsigned short* __restrict__ W_hh0,
    const unsigned short* __restrict__ W_ih1,
    const unsigned short* __restrict__ W_hh1,
    const float* __restrict__ b_ih1,
    const float* __restrict__ b_hh1,
    int* __restrict__ flags) {               // 64 flags
  __shared__ unsigned short X_lds[4][2064];  // 4 batches x 2048 k (+16 pad: stride=8 mod 32 dw)
  __shared__ float red0[8][4][16][4];        // 8 KB
  __shared__ float red1[8][4][16][4];        // 8 KB
  __shared__ float gsum[2][4][16][4];        // 2 KB
  int tid = threadIdx.x;
  int lane = tid & 63, w = tid >> 6;
  int bid = blockIdx.x;                      // 0..63
  int base = bid * 16;

  // ---- preload weight B-frags (fragment scheme identical to passing r5-r7 kernel) ----
  bf16x8 wf0[4][4];    // [gate][ks], layer0: K=128 per wave
  bf16x8 wf1[4][8];    // layer1: K=256 per wave (k<1024 -> Wih1, else Whh1)
  int ch = lane & 15;
  int kb0 = w * 128, kb1 = w * 256;
  int klo = (lane >> 4) << 3;
#pragma unroll
  for (int nt = 0; nt < 4; nt++) {
    int grow = nt * 1024 + base + ch;
#pragma unroll
    for (int ks = 0; ks < 4; ks++)
      wf0[nt][ks] = *(const bf16x8*)(W_hh0 + (size_t)grow * 1024 + kb0 + ks * 32 + klo);
#pragma unroll
    for (int ks = 0; ks < 8; ks++) {
      int k = kb1 + ks * 32 + klo;
      const unsigned short* src = (k < 1024) ? (W_ih1 + (size_t)grow * 1024 + k)
                                             : (W_hh1 + (size_t)grow * 1024 + (k - 1024));
      wf1[nt][ks] = *(const bf16x8*)src;
    }
  }

  // gate-thread persistent state: tid<64 -> layer0 (ch=tid>>2, b=tid&3); 64..127 -> layer1
  float creg = 0.f;
  float bs0 = 0.f, bs1 = 0.f, bs2 = 0.f, bs3 = 0.f;
  int gch = (tid & 63) >> 2, gb = tid & 3;
  if (tid >= 64 && tid < 128) {
    int c = base + gch;
    bs0 = b_ih1[c] + b_hh1[c];
    bs1 = b_ih1[1024 + c] + b_hh1[1024 + c];
    bs2 = b_ih1[2048 + c] + b_hh1[2048 + c];
    bs3 = b_ih1[3072 + c] + b_hh1[3072 + c];
  }

  int ar = ch & 3;                           // clamped A-row (batch); D rows 4-15 unused
  for (int p = 0; p <= 64; p++) {
    bool act0 = (p < 64), act1 = (p >= 1);
    // ---- wait: all 64 blocks posted round p-1 (=> h0h[p], h1h[p-1] at IC) ----
    if (p > 0) {
      if (w == 0) {
        while (true) {
          int f = __hip_atomic_load(&flags[lane], __ATOMIC_RELAXED, __HIP_MEMORY_SCOPE_AGENT);
          if (__all(f >= p)) break;
          __builtin_amdgcn_s_sleep(1);
        }
      }
      __syncthreads();
    }
    // ---- stage X = [h0h[p] | h1h[p-1]] as bf16, 4x2048 ----
    {
      int b = tid >> 7, k0 = (tid & 127) * 16;
      if (k0 < 1024 || act1) {
        const float* fsrc = (k0 < 1024) ? (h0h + (size_t)p * 4096 + b * 1024 + k0)
                                        : (h1h + (size_t)(p - 1) * 4096 + b * 1024 + (k0 - 1024));
        const unsigned long long* s8 = (const unsigned long long*)fsrc;
        unsigned long long v[8];
#pragma unroll
        for (int i = 0; i < 8; i++)
          v[i] = __hip_atomic_load(s8 + i, __ATOMIC_RELAXED, __HIP_MEMORY_SCOPE_AGENT);
        bf16x8 r0, r1;
#pragma unroll
        for (int i = 0; i < 4; i++) {
          union { unsigned long long u; float f[2]; } cv; cv.u = v[i];
          r0[2 * i] = (short)f2bf(cv.f[0]); r0[2 * i + 1] = (short)f2bf(cv.f[1]);
        }
#pragma unroll
        for (int i = 0; i < 4; i++) {
          union { unsigned long long u; float f[2]; } cv; cv.u = v[4 + i];
          r1[2 * i] = (short)f2bf(cv.f[0]); r1[2 * i + 1] = (short)f2bf(cv.f[1]);
        }
        *(bf16x8*)&X_lds[b][k0] = r0;
        *(bf16x8*)&X_lds[b][k0 + 8] = r1;
      }
    }
    __syncthreads();

    // ---- layer0 MFMA: gates(16x64) partial over this wave's K=128 ----
    if (act0) {
      f32x4 acc[4];
#pragma unroll
      for (int nt = 0; nt < 4; nt++) acc[nt] = (f32x4){0.f, 0.f, 0.f, 0.f};
#pragma unroll
      for (int ks = 0; ks < 4; ks++) {
        bf16x8 a = *(const bf16x8*)&X_lds[ar][kb0 + ks * 32 + klo];
#pragma unroll
        for (int nt = 0; nt < 4; nt++)
          acc[nt] = __builtin_amdgcn_mfma_f32_16x16x32_bf16(a, wf0[nt][ks], acc[nt], 0, 0, 0);
      }
      if (lane < 16) {
#pragma unroll
        for (int nt = 0; nt < 4; nt++) *(f32x4*)&red0[w][nt][lane][0] = acc[nt];
      }
    }
    // ---- layer1 MFMA: K=256 per wave over combined [h0|h1] ----
    if (act1) {
      f32x4 acc[4];
#pragma unroll
      for (int nt = 0; nt < 4; nt++) acc[nt] = (f32x4){0.f, 0.f, 0.f, 0.f};
#pragma unroll
      for (int ks = 0; ks < 8; ks++) {
        bf16x8 a = *(const bf16x8*)&X_lds[ar][kb1 + ks * 32 + klo];
#pragma unroll
        for (int nt = 0; nt < 4; nt++)
          acc[nt] = __builtin_amdgcn_mfma_f32_16x16x32_bf16(a, wf1[nt][ks], acc[nt], 0, 0, 0);
      }
      if (lane < 16) {
#pragma unroll
        for (int nt = 0; nt < 4; nt++) *(f32x4*)&red1[w][nt][lane][0] = acc[nt];
      }
    }
    __syncthreads();
    // ---- reduce 8 wave-partials (all 512 threads: 2 layers x 4 gates x 16 ch x 4 b) ----
    {
      int layer = tid >> 8, nt = (tid >> 6) & 3, cc = (tid >> 2) & 15, q = tid & 3;
      const float (*rp)[4][16][4] = layer ? red1 : red0;
      float s = 0.f;
#pragma unroll
      for (int w8 = 0; w8 < 8; w8++) s += rp[w8][nt][cc][q];
      gsum[layer][nt][cc][q] = s;
    }
    __syncthreads();
    // ---- gate nonlinearity + h writes (128 threads) ----
    if (tid < 128) {
      int layer = tid >> 6;
      bool act = layer ? act1 : act0;
      if (act) {
        float gi = gsum[layer][0][gch][gb], gf = gsum[layer][1][gch][gb];
        float gg = gsum[layer][2][gch][gb], go = gsum[layer][3][gch][gb];
        if (layer == 0) {
          const float* x0p = X0 + ((size_t)(gb * 64 + p)) * 4096 + base + gch;
          gi += x0p[0]; gf += x0p[1024]; gg += x0p[2048]; go += x0p[3072];
        } else {
          gi += bs0; gf += bs1; gg += bs2; go += bs3;
        }
        float ii = 1.f / (1.f + __expf(-gi));
        float ff = 1.f / (1.f + __expf(-gf));
        float oo = 1.f / (1.f + __expf(-go));
        float cn = ff * creg + ii * tanhf(gg);
        creg = cn;
        float hn = oo * tanhf(cn);
        if (layer == 0) {
          __hip_atomic_store(&h0h[(size_t)(p + 1) * 4096 + gb * 1024 + base + gch], hn,
                             __ATOMIC_RELAXED, __HIP_MEMORY_SCOPE_AGENT);
        } else {
          __hip_atomic_store(&h1h[(size_t)p * 4096 + gb * 1024 + base + gch], hn,
                             __ATOMIC_RELAXED, __HIP_MEMORY_SCOPE_AGENT);
          hdec[((size_t)(gb * 64 + (p - 1))) * 1024 + base + gch] = hn;
        }
      }
    }
    // ---- arrival: flush h stores (each wave drains own vmcnt before barrier) ----
    asm volatile("s_waitcnt vmcnt(0)" ::: "memory");
    __syncthreads();
    if (tid == 0 && p < 64)
      __hip_atomic_store(&flags[bid], p + 1, __ATOMIC_RELAXED, __HIP_MEMORY_SCOPE_AGENT);
  }
}

// ---------------- joint: out[b,t,u,:] = tanh(encp[b,t,:]+decp[b,u,:]) @ Wout^T + bout ----
// 256 blocks x 512 threads; z-panel in regs; NONTEMPORAL f32 output stores.
__global__ __launch_bounds__(512) void k_joint(const float* __restrict__ encp,   // (B,T,512)
                                               const float* __restrict__ decp,   // (B,U,512)
                                               const unsigned short* __restrict__ Wout, // (2048,512) bf16
                                               const float* __restrict__ bout,   // (2048) f32
                                               float* __restrict__ out) {        // (B,T,U,2048) f32
  __shared__ unsigned short Wls[2][8192];   // 2 x 16KB: 128 n-rows x 64 k (swizzled)
  int tid = threadIdx.x;
  int lane = tid & 63, wid = tid >> 6;      // 8 waves
  int bidx = blockIdx.x;
  int b = bidx >> 6, tloc = bidx & 63;
  int t0 = tloc * 2;
  int wm = (wid >> 1) * 32;                 // 4 m-waves x 32 rows
  int wn = (wid & 1) * 64;                  // 2 n-waves x 64 cols

  // ---- prologue: issue stage of chunk 0 (overlaps with A-build) ----
  {
#pragma unroll
    for (int q = 0; q < 2; q++) {
      int idx = tid + q * 512;
      int n = idx >> 3, sl = idx & 7;
      int ss = sl ^ (n & 7);
      gload_lds16(Wout + (size_t)n * 512 + ss * 8, &Wls[0][idx * 8]);
    }
  }

  // ---- build A panel in registers: 2 m-frags x 16 k-frags, bf16x8 each ----
  bf16x8 afr[32];
#pragma unroll
  for (int mf = 0; mf < 2; mf++) {
    int rr = wm + mf * 16 + (lane & 15);
    int t = t0 + (rr >> 6), u = rr & 63;
    const float* ep = encp + ((size_t)(b * 128 + t)) * 512;
    const float* dp = decp + ((size_t)(b * 64 + u)) * 512;
#pragma unroll
    for (int kf = 0; kf < 16; kf++) {
      int k0 = kf * 32 + ((lane >> 4) << 3);
      bf16x8 v;
#pragma unroll
      for (int j = 0; j < 8; j++) {
        float x = ep[k0 + j] + dp[k0 + j];
        float e = __expf(x + x);
        v[j] = (short)f2bf(1.f - 2.f / (e + 1.f));
      }
      afr[mf * 16 + kf] = v;
    }
  }

  f32x4 acc[2][4];
#pragma unroll
  for (int mf = 0; mf < 2; mf++)
#pragma unroll
    for (int nf = 0; nf < 4; nf++) acc[mf][nf] = (f32x4){0.f, 0.f, 0.f, 0.f};

  // ---- main loop: 16 n-tiles x 8 k-chunks, depth-1 prefetch ----
  for (int c = 0; c < 128; c++) {
    int nt = c >> 3, kc = c & 7;
    __syncthreads();                    // drains vmcnt(0): chunk c is in LDS
    if (c < 127) {
      int c1i = c + 1;
      int nn0 = (c1i >> 3) << 7;
      int kb = (c1i & 7) * 64;
      unsigned short* dst = Wls[c1i & 1];
#pragma unroll
      for (int q = 0; q < 2; q++) {
        int idx = tid + q * 512;
        int n = idx >> 3, sl = idx & 7;
        int ss = sl ^ (n & 7);
        gload_lds16(Wout + (size_t)(nn0 + n) * 512 + kb + ss * 8, dst + idx * 8);
      }
    }
    const unsigned short* Wb = Wls[c & 1];
#pragma unroll
    for (int ks = 0; ks < 2; ks++) {
      bf16x8 bfr[4];
#pragma unroll
      for (int nf = 0; nf < 4; nf++) {
        int n = wn + nf * 16 + (lane & 15);
        int slot = ks * 4 + (lane >> 4);
        int phys = slot ^ (n & 7);
        bfr[nf] = *(const bf16x8*)(Wb + n * 64 + phys * 8);
      }
      int kf = kc * 2 + ks;
#pragma unroll
      for (int mf = 0; mf < 2; mf++)
#pragma unroll
        for (int nf = 0; nf < 4; nf++)
          acc[mf][nf] = __builtin_amdgcn_mfma_f32_16x16x32_bf16(afr[mf * 16 + kf], bfr[nf],
                                                                acc[mf][nf], 0, 0, 0);
    }
    if (kc == 7) {                      // epilogue for this n-tile
      int n0 = nt << 7;
#pragma unroll
      for (int mf = 0; mf < 2; mf++) {
        int rb = wm + mf * 16 + ((lane >> 4) << 2);
#pragma unroll
        for (int nf = 0; nf < 4; nf++) {
          int o = n0 + wn + nf * 16 + (lane & 15);
          float bb = bout[o];
#pragma unroll
          for (int q = 0; q < 4; q++) {
            int rr = rb + q;
            int t = t0 + (rr >> 6), u = rr & 63;
            __builtin_nontemporal_store(acc[mf][nf][q] + bb,
                &out[(((size_t)(b * 128 + t)) * 64 + u) * 2048 + o]);
          }
          acc[mf][nf] = (f32x4){0.f, 0.f, 0.f, 0.f};
        }
      }
    }
  }
}

// ---------------- launch ----------------
extern "C" void kernel_launch(void* const* d_in, const int* in_sizes, int n_in,
                              void* d_out, int out_size, void* d_ws, size_t ws_size,
                              hipStream_t stream) {
  const float* hs   = (const float*)d_in[0];
  const int*   ys   = (const int*)d_in[1];
  const float* emb  = (const float*)d_in[2];
  const float* Wih0 = (const float*)d_in[3];
  const float* Whh0 = (const float*)d_in[4];
  const float* bih0 = (const float*)d_in[5];
  const float* bhh0 = (const float*)d_in[6];
  const float* Wih1 = (const float*)d_in[7];
  const float* Whh1 = (const float*)d_in[8];
  const float* bih1 = (const float*)d_in[9];
  const float* bhh1 = (const float*)d_in[10];
  const float* Wenc = (const float*)d_in[11];
  const float* benc = (const float*)d_in[12];
  const float* Wdec = (const float*)d_in[13];
  const float* Wout = (const float*)d_in[14];
  const float* bout = (const float*)d_in[15];

  char* ws = (char*)d_ws;
  float*          eys   = (float*)(ws + 0);            // 256x512 f32        = 524,288
  float*          X0    = (float*)(ws + 524288);       // 256x4096 f32       = 4,194,304
  float*          encp  = (float*)(ws + 4718592);      // 512x512 f32        = 1,048,576
  float*          decp  = (float*)(ws + 5767168);      // 256x512 f32        = 524,288
  float*          h0h   = (float*)(ws + 6291456);      // 65x4096 f32        = 1,064,960
  float*          h1h   = (float*)(ws + 7356416);      // 65x4096 f32        = 1,064,960
  float*          hdec  = (float*)(ws + 8421376);      // 256x1024 f32       = 1,048,576
  int*            flags = (int*)(ws + 9469952);        // 64 ints
  unsigned short* Whh0b = (unsigned short*)(ws + 9502720);   // 4M bf16      = 8,388,608
  unsigned short* Wih1b = (unsigned short*)(ws + 17891328);  // 4M bf16      = 8,388,608
  unsigned short* Whh1b = (unsigned short*)(ws + 26279936);  // 4M bf16      = 8,388,608
  unsigned short* Woutb = (unsigned short*)(ws + 34668544);  // 1M bf16      = 2,097,152
  float*          out   = (float*)d_out;                     // total ws = 36,765,696 B

  // weight conversion (bf16 for LSTM recurrent mats + Wout for global_load_lds)
  k_cvt<<<6656, 256, 0, stream>>>(Whh0, Wih1, Whh1, Wout, Whh0b, Wih1b, Whh1b, Woutb);
  k_prep<<<64, 256, 0, stream>>>(ys, emb, eys, h0h, h1h, flags);
  // X0 = eys @ Wih0^T + bih0 + bhh0   (M=256, N=4096, K=512)
  k_gemm_bias<<<256, 256, 0, stream>>>(eys, Wih0, bih0, bhh0, X0, 256, 4096, 512);
  // encp = hs @ Wenc^T + benc         (M=512, N=512, K=512)
  k_gemm_bias<<<64, 256, 0, stream>>>(hs, Wenc, benc, nullptr, encp, 512, 512, 512);
  // fused LSTM v3: 64 merged blocks, single sync domain
  k_lstm_fused<<<64, 512, 0, stream>>>(X0, h0h, h1h, hdec,
                                       Whh0b, Wih1b, Whh1b, bih1, bhh1, flags);
  // decp = hdec @ Wdec^T              (M=256, N=512, K=1024)
  k_gemm_bias<<<32, 256, 0, stream>>>(hdec, Wdec, nullptr, nullptr, decp, 256, 512, 1024);
  // joint
  k_joint<<<256, 512, 0, stream>>>(encp, decp, Woutb, bout, out);
}